// Round 1
// baseline (8748.491 us; speedup 1.0000x reference)
//
#include <hip/hip_runtime.h>
#include <hip/hip_bf16.h>
#include <math.h>

#define N_NODES 100000
#define N_EDGES 1600000
#define F_IN 256
#define H_DIM 128
#define N_GRAPHS 1000

// ---------------- degree / norm ----------------
__global__ void k_init_deg(float* __restrict__ deg) {
    int i = blockIdx.x * blockDim.x + threadIdx.x;
    if (i < N_NODES) deg[i] = 1.0f;  // self-loop
}

__global__ void k_deg_atomic(const int* __restrict__ dst, float* __restrict__ deg) {
    int i = blockIdx.x * blockDim.x + threadIdx.x;
    if (i < N_EDGES) atomicAdd(&deg[dst[i]], 1.0f);
}

__global__ void k_dis(const float* __restrict__ deg, float* __restrict__ dis) {
    int i = blockIdx.x * blockDim.x + threadIdx.x;
    if (i < N_NODES) {
        float d = deg[i];
        dis[i] = d > 0.0f ? rsqrtf(d) : 0.0f;
    }
}

// ---------------- GEMM: C[M,128] = A[M,K] @ W[K,128], optional relu(A) ----------------
// block 256 threads, tile 128x128, BK=32, per-thread 8x8.
template <int K, bool RELU>
__global__ __launch_bounds__(256, 2) void k_mm(const float* __restrict__ A,
                                               const float* __restrict__ W,
                                               float* __restrict__ C, int M) {
    __shared__ float As[32 * 132];  // [k][r] transposed, pad stride 132
    __shared__ float Ws[32 * 144];  // [k][c'] group-staggered: c' = c + 4*(c>>5)
    const int t = threadIdx.x;
    const int tx = t & 15;   // col group
    const int ty = t >> 4;   // row group
    const int row0 = blockIdx.x * 128;

    float acc[8][8];
#pragma unroll
    for (int i = 0; i < 8; ++i)
#pragma unroll
        for (int j = 0; j < 8; ++j) acc[i][j] = 0.0f;

    for (int k0 = 0; k0 < K; k0 += 32) {
        // ---- load W slab (32 x 128) ----
        {
            int idx = t;
#pragma unroll
            for (int i = 0; i < 4; ++i, idx += 256) {
                int k = idx >> 5, q = idx & 31;
                int c = q << 2;
                float4 v = *(const float4*)&W[(k0 + k) * 128 + c];
                int cs = c + ((c >> 5) << 2);
                *(float4*)&Ws[k * 144 + cs] = v;
            }
        }
        // ---- load A slab (128 rows x 32 k), store transposed As[k][r] ----
        {
            int idx = t;
#pragma unroll
            for (int i = 0; i < 4; ++i, idx += 256) {
                int r = idx >> 3, q = idx & 7;
                int gr = row0 + r;
                float4 v = make_float4(0.f, 0.f, 0.f, 0.f);
                if (gr < M) v = *(const float4*)&A[(long)gr * K + k0 + (q << 2)];
                if (RELU) {
                    v.x = fmaxf(v.x, 0.f); v.y = fmaxf(v.y, 0.f);
                    v.z = fmaxf(v.z, 0.f); v.w = fmaxf(v.w, 0.f);
                }
                int kb = q << 2;
                As[(kb + 0) * 132 + r] = v.x;
                As[(kb + 1) * 132 + r] = v.y;
                As[(kb + 2) * 132 + r] = v.z;
                As[(kb + 3) * 132 + r] = v.w;
            }
        }
        __syncthreads();
#pragma unroll
        for (int k = 0; k < 32; ++k) {
            const float* ap = &As[k * 132 + ty * 8];
            float4 a0 = *(const float4*)ap;
            float4 a1 = *(const float4*)(ap + 4);
            const float* wp = &Ws[k * 144 + tx * 8 + ((tx >> 2) << 2)];
            float4 w0 = *(const float4*)wp;
            float4 w1 = *(const float4*)(wp + 4);
            float av[8] = {a0.x, a0.y, a0.z, a0.w, a1.x, a1.y, a1.z, a1.w};
            float wv[8] = {w0.x, w0.y, w0.z, w0.w, w1.x, w1.y, w1.z, w1.w};
#pragma unroll
            for (int i = 0; i < 8; ++i)
#pragma unroll
                for (int j = 0; j < 8; ++j) acc[i][j] += av[i] * wv[j];
        }
        __syncthreads();
    }
    // ---- store ----
#pragma unroll
    for (int i = 0; i < 8; ++i) {
        int r = row0 + ty * 8 + i;
        if (r < M) {
            float4 o0 = make_float4(acc[i][0], acc[i][1], acc[i][2], acc[i][3]);
            float4 o1 = make_float4(acc[i][4], acc[i][5], acc[i][6], acc[i][7]);
            *(float4*)&C[(long)r * 128 + tx * 8] = o0;
            *(float4*)&C[(long)r * 128 + tx * 8 + 4] = o1;
        }
    }
}

// ---------------- self-loop init: acc = t*dis^2 + b ----------------
__global__ void k_self_init(const float* __restrict__ tbuf, const float* __restrict__ dis,
                            const float* __restrict__ b, float* __restrict__ acc) {
    int idx = blockIdx.x * blockDim.x + threadIdx.x;  // N*32
    if (idx >= N_NODES * 32) return;
    int n = idx >> 5, q = (idx & 31) << 2;
    float dn = dis[n];
    float s = dn * dn;
    float4 v = *(const float4*)&tbuf[(long)n * 128 + q];
    float4 bb = *(const float4*)&b[q];
    float4 o;
    o.x = v.x * s + bb.x; o.y = v.y * s + bb.y;
    o.z = v.z * s + bb.z; o.w = v.w * s + bb.w;
    *(float4*)&acc[(long)n * 128 + q] = o;
}

// ---------------- edge scatter: acc[dst] += t[src] * dis[src]*dis[dst] ----------------
__global__ void k_scatter(const int* __restrict__ src, const int* __restrict__ dst,
                          const float* __restrict__ dis, const float* __restrict__ tbuf,
                          float* __restrict__ acc) {
    long idx = (long)blockIdx.x * blockDim.x + threadIdx.x;  // E*32
    if (idx >= (long)N_EDGES * 32) return;
    int e = (int)(idx >> 5), q = ((int)idx & 31) << 2;
    int s = src[e], d = dst[e];
    float nrm = dis[s] * dis[d];
    float4 v = *(const float4*)&tbuf[(long)s * 128 + q];
    float* ap = &acc[(long)d * 128 + q];
    atomicAdd(ap + 0, v.x * nrm);
    atomicAdd(ap + 1, v.y * nrm);
    atomicAdd(ap + 2, v.z * nrm);
    atomicAdd(ap + 3, v.w * nrm);
}

// ---------------- pooling ----------------
__global__ void k_zero_pool(float* __restrict__ pools, float* __restrict__ counts) {
    int i = blockIdx.x * blockDim.x + threadIdx.x;
    if (i < N_GRAPHS * 128) pools[i] = 0.0f;
    if (i < N_GRAPHS) counts[i] = 0.0f;
}

__global__ void k_pool(const int* __restrict__ batch, const float* __restrict__ h,
                       float* __restrict__ pools, float* __restrict__ counts) {
    int idx = blockIdx.x * blockDim.x + threadIdx.x;  // N*32
    if (idx >= N_NODES * 32) return;
    int n = idx >> 5, qi = idx & 31;
    int q = qi << 2;
    int g = batch[n];
    float4 v = *(const float4*)&h[(long)n * 128 + q];
    float* pp = &pools[(long)g * 128 + q];
    atomicAdd(pp + 0, fmaxf(v.x, 0.f));
    atomicAdd(pp + 1, fmaxf(v.y, 0.f));
    atomicAdd(pp + 2, fmaxf(v.z, 0.f));
    atomicAdd(pp + 3, fmaxf(v.w, 0.f));
    if (qi == 0) atomicAdd(&counts[g], 1.0f);
}

// ---------------- head: mean -> fc1 relu -> fc2 -> log_softmax ----------------
__global__ __launch_bounds__(64) void k_head(const float* __restrict__ pools,
                                             const float* __restrict__ counts,
                                             const float* __restrict__ fw1, const float* __restrict__ fb1,
                                             const float* __restrict__ fw2, const float* __restrict__ fb2,
                                             float* __restrict__ out) {
    int g = blockIdx.x;
    int t = threadIdx.x;
    __shared__ float sg[128];
    __shared__ float sh[32];
    float cnt = fmaxf(counts[g], 1.0f);
    float inv = 1.0f / cnt;
    sg[t] = pools[(long)g * 128 + t] * inv;
    sg[t + 64] = pools[(long)g * 128 + 64 + t] * inv;
    __syncthreads();
    if (t < 32) {
        float a = fb1[t];
        for (int k = 0; k < 128; ++k) a += sg[k] * fw1[k * 32 + t];
        sh[t] = fmaxf(a, 0.f);
    }
    __syncthreads();
    if (t == 0) {
        float l0 = fb2[0], l1 = fb2[1];
        for (int k = 0; k < 32; ++k) {
            l0 += sh[k] * fw2[k * 2];
            l1 += sh[k] * fw2[k * 2 + 1];
        }
        float m = fmaxf(l0, l1);
        float lse = m + logf(expf(l0 - m) + expf(l1 - m));
        out[g * 2 + 0] = l0 - lse;
        out[g * 2 + 1] = l1 - lse;
    }
}

extern "C" void kernel_launch(void* const* d_in, const int* in_sizes, int n_in,
                              void* d_out, int out_size, void* d_ws, size_t ws_size,
                              hipStream_t stream) {
    const float* x  = (const float*)d_in[0];
    const int* ei   = (const int*)d_in[1];
    const int* batch = (const int*)d_in[2];
    const float* W1 = (const float*)d_in[3];
    const float* b1 = (const float*)d_in[4];
    const float* W2 = (const float*)d_in[5];
    const float* b2 = (const float*)d_in[6];
    const float* W3 = (const float*)d_in[7];
    const float* b3 = (const float*)d_in[8];
    const float* fw1 = (const float*)d_in[9];
    const float* fb1 = (const float*)d_in[10];
    const float* fw2 = (const float*)d_in[11];
    const float* fb2 = (const float*)d_in[12];
    float* out = (float*)d_out;

    const int* src = ei;             // edge_index[0]
    const int* dst = ei + N_EDGES;   // edge_index[1]

    // workspace layout (floats)
    float* ws = (float*)d_ws;
    float* deg   = ws;                              // N
    float* dis   = deg + N_NODES;                   // N
    float* buf0  = dis + N_NODES;                   // N*128  (t = h@W)
    float* buf1  = buf0 + (long)N_NODES * 128;      // N*128  (acc / h)
    float* pools = buf1 + (long)N_NODES * 128;      // G*128
    float* cnts  = pools + (long)N_GRAPHS * 128;    // G

    const int B = 256;
    // degree + norm
    k_init_deg<<<(N_NODES + B - 1) / B, B, 0, stream>>>(deg);
    k_deg_atomic<<<(N_EDGES + B - 1) / B, B, 0, stream>>>(dst, deg);
    k_dis<<<(N_NODES + B - 1) / B, B, 0, stream>>>(deg, dis);

    const int mmGrid = (N_NODES + 127) / 128;
    const int nThreads32 = N_NODES * 32;
    const long eThreads32 = (long)N_EDGES * 32;

    // layer 1: t = x @ W1 ; acc = t*dis^2 + b1 ; scatter ; (relu fused downstream)
    k_mm<F_IN, false><<<mmGrid, 256, 0, stream>>>(x, W1, buf0, N_NODES);
    k_self_init<<<(nThreads32 + B - 1) / B, B, 0, stream>>>(buf0, dis, b1, buf1);
    k_scatter<<<(int)((eThreads32 + B - 1) / B), B, 0, stream>>>(src, dst, dis, buf0, buf1);

    // layer 2 (relu of previous h fused into A-read)
    k_mm<H_DIM, true><<<mmGrid, 256, 0, stream>>>(buf1, W2, buf0, N_NODES);
    k_self_init<<<(nThreads32 + B - 1) / B, B, 0, stream>>>(buf0, dis, b2, buf1);
    k_scatter<<<(int)((eThreads32 + B - 1) / B), B, 0, stream>>>(src, dst, dis, buf0, buf1);

    // layer 3
    k_mm<H_DIM, true><<<mmGrid, 256, 0, stream>>>(buf1, W3, buf0, N_NODES);
    k_self_init<<<(nThreads32 + B - 1) / B, B, 0, stream>>>(buf0, dis, b3, buf1);
    k_scatter<<<(int)((eThreads32 + B - 1) / B), B, 0, stream>>>(src, dst, dis, buf0, buf1);

    // pool (relu fused) + head
    k_zero_pool<<<(N_GRAPHS * 128 + B - 1) / B, B, 0, stream>>>(pools, cnts);
    k_pool<<<(nThreads32 + B - 1) / B, B, 0, stream>>>(batch, buf1, pools, cnts);
    k_head<<<N_GRAPHS, 64, 0, stream>>>(pools, cnts, fw1, fb1, fw2, fb2, out);
}

// Round 2
// 1187.915 us; speedup vs baseline: 7.3646x; 7.3646x over previous
//
#include <hip/hip_runtime.h>
#include <hip/hip_bf16.h>
#include <math.h>

#define N_NODES 100000
#define N_EDGES 1600000
#define F_IN 256
#define H_DIM 128
#define N_GRAPHS 1000
#define SCAN_CHUNK 1024
#define SCAN_BLOCKS ((N_NODES + SCAN_CHUNK - 1) / SCAN_CHUNK)  // 98

// ---------------- CSR build ----------------
__global__ void k_zero_cnt(int* __restrict__ cnt) {
    int i = blockIdx.x * blockDim.x + threadIdx.x;
    if (i < N_NODES) cnt[i] = 0;
}

__global__ void k_cnt(const int* __restrict__ dst, int* __restrict__ cnt) {
    int i = blockIdx.x * blockDim.x + threadIdx.x;
    if (i < N_EDGES) atomicAdd(&cnt[dst[i]], 1);
}

__global__ void k_dis(const int* __restrict__ cnt, float* __restrict__ dis) {
    int i = blockIdx.x * blockDim.x + threadIdx.x;
    if (i < N_NODES) dis[i] = rsqrtf((float)(cnt[i] + 1));  // +1 self-loop, always > 0
}

// block = 256 threads, chunk = 1024 elements; local exclusive scan -> row_ptr, block sum -> partial
__global__ __launch_bounds__(256) void k_scan1(const int* __restrict__ cnt,
                                               int* __restrict__ row_ptr,
                                               int* __restrict__ partial) {
    __shared__ int s[256];
    const int t = threadIdx.x;
    const int base = blockIdx.x * SCAN_CHUNK + t * 4;
    int c0 = 0, c1 = 0, c2 = 0, c3 = 0;
    if (base + 0 < N_NODES) c0 = cnt[base + 0];
    if (base + 1 < N_NODES) c1 = cnt[base + 1];
    if (base + 2 < N_NODES) c2 = cnt[base + 2];
    if (base + 3 < N_NODES) c3 = cnt[base + 3];
    int mySum = c0 + c1 + c2 + c3;
    s[t] = mySum;
    __syncthreads();
    for (int off = 1; off < 256; off <<= 1) {
        int v = (t >= off) ? s[t - off] : 0;
        __syncthreads();
        s[t] += v;
        __syncthreads();
    }
    int excl = s[t] - mySum;
    if (base + 0 < N_NODES) row_ptr[base + 0] = excl;
    excl += c0;
    if (base + 1 < N_NODES) row_ptr[base + 1] = excl;
    excl += c1;
    if (base + 2 < N_NODES) row_ptr[base + 2] = excl;
    excl += c2;
    if (base + 3 < N_NODES) row_ptr[base + 3] = excl;
    if (t == 255) partial[blockIdx.x] = s[255];
}

// single block scans the 98 partials (exclusive)
__global__ __launch_bounds__(128) void k_scan2(int* __restrict__ partial, int* __restrict__ row_ptr) {
    __shared__ int s[128];
    const int t = threadIdx.x;
    int v = (t < SCAN_BLOCKS) ? partial[t] : 0;
    int mine = v;
    s[t] = v;
    __syncthreads();
    for (int off = 1; off < 128; off <<= 1) {
        int u = (t >= off) ? s[t - off] : 0;
        __syncthreads();
        s[t] += u;
        __syncthreads();
    }
    if (t < SCAN_BLOCKS) partial[t] = s[t] - mine;  // exclusive
    if (t == 0) row_ptr[N_NODES] = N_EDGES;
}

__global__ __launch_bounds__(256) void k_scan3(int* __restrict__ row_ptr, int* __restrict__ cursor,
                                               const int* __restrict__ partial) {
    const int t = threadIdx.x;
    const int base = blockIdx.x * SCAN_CHUNK + t * 4;
    int add = partial[blockIdx.x];
#pragma unroll
    for (int i = 0; i < 4; ++i) {
        int idx = base + i;
        if (idx < N_NODES) {
            int v = row_ptr[idx] + add;
            row_ptr[idx] = v;
            cursor[idx] = v;
        }
    }
}

__global__ void k_fill(const int* __restrict__ src, const int* __restrict__ dst,
                       int* __restrict__ cursor, int* __restrict__ col) {
    int e = blockIdx.x * blockDim.x + threadIdx.x;
    if (e < N_EDGES) {
        int d = dst[e];
        int pos = atomicAdd(&cursor[d], 1);
        col[pos] = src[e];
    }
}

// ---------------- GEMM: C[M,128] = A[M,K] @ W[K,128], optional relu(A) ----------------
template <int K, bool RELU>
__global__ __launch_bounds__(256, 2) void k_mm(const float* __restrict__ A,
                                               const float* __restrict__ W,
                                               float* __restrict__ C, int M) {
    __shared__ float As[32 * 132];
    __shared__ float Ws[32 * 144];
    const int t = threadIdx.x;
    const int tx = t & 15;
    const int ty = t >> 4;
    const int row0 = blockIdx.x * 128;

    float acc[8][8];
#pragma unroll
    for (int i = 0; i < 8; ++i)
#pragma unroll
        for (int j = 0; j < 8; ++j) acc[i][j] = 0.0f;

    for (int k0 = 0; k0 < K; k0 += 32) {
        {
            int idx = t;
#pragma unroll
            for (int i = 0; i < 4; ++i, idx += 256) {
                int k = idx >> 5, q = idx & 31;
                int c = q << 2;
                float4 v = *(const float4*)&W[(k0 + k) * 128 + c];
                int cs = c + ((c >> 5) << 2);
                *(float4*)&Ws[k * 144 + cs] = v;
            }
        }
        {
            int idx = t;
#pragma unroll
            for (int i = 0; i < 4; ++i, idx += 256) {
                int r = idx >> 3, q = idx & 7;
                int gr = row0 + r;
                float4 v = make_float4(0.f, 0.f, 0.f, 0.f);
                if (gr < M) v = *(const float4*)&A[(long)gr * K + k0 + (q << 2)];
                if (RELU) {
                    v.x = fmaxf(v.x, 0.f); v.y = fmaxf(v.y, 0.f);
                    v.z = fmaxf(v.z, 0.f); v.w = fmaxf(v.w, 0.f);
                }
                int kb = q << 2;
                As[(kb + 0) * 132 + r] = v.x;
                As[(kb + 1) * 132 + r] = v.y;
                As[(kb + 2) * 132 + r] = v.z;
                As[(kb + 3) * 132 + r] = v.w;
            }
        }
        __syncthreads();
#pragma unroll
        for (int k = 0; k < 32; ++k) {
            const float* ap = &As[k * 132 + ty * 8];
            float4 a0 = *(const float4*)ap;
            float4 a1 = *(const float4*)(ap + 4);
            const float* wp = &Ws[k * 144 + tx * 8 + ((tx >> 2) << 2)];
            float4 w0 = *(const float4*)wp;
            float4 w1 = *(const float4*)(wp + 4);
            float av[8] = {a0.x, a0.y, a0.z, a0.w, a1.x, a1.y, a1.z, a1.w};
            float wv[8] = {w0.x, w0.y, w0.z, w0.w, w1.x, w1.y, w1.z, w1.w};
#pragma unroll
            for (int i = 0; i < 8; ++i)
#pragma unroll
                for (int j = 0; j < 8; ++j) acc[i][j] += av[i] * wv[j];
        }
        __syncthreads();
    }
#pragma unroll
    for (int i = 0; i < 8; ++i) {
        int r = row0 + ty * 8 + i;
        if (r < M) {
            float4 o0 = make_float4(acc[i][0], acc[i][1], acc[i][2], acc[i][3]);
            float4 o1 = make_float4(acc[i][4], acc[i][5], acc[i][6], acc[i][7]);
            *(float4*)&C[(long)r * 128 + tx * 8] = o0;
            *(float4*)&C[(long)r * 128 + tx * 8 + 4] = o1;
        }
    }
}

// ---------------- CSR gather aggregation: h[n] = sum_{e in CSR[n]} t[src]*dis[src]*dis[n]
//                  + t[n]*dis[n]^2 + b   (self-loop + bias fused) ----------------
__global__ __launch_bounds__(256) void k_agg(const int* __restrict__ row_ptr,
                                             const int* __restrict__ col,
                                             const float* __restrict__ dis,
                                             const float* __restrict__ tbuf,
                                             const float* __restrict__ b,
                                             float* __restrict__ h) {
    const int t = threadIdx.x;
    const int node = blockIdx.x * 8 + (t >> 5);  // 8 nodes per block
    const int lane = t & 31;
    if (node >= N_NODES) return;
    const int q = lane << 2;  // channel offset (float4)
    const float dn = dis[node];

    float4 acc = *(const float4*)&tbuf[(long)node * 128 + q];
    const float s2 = dn * dn;
    float4 bb = *(const float4*)&b[q];
    acc.x = acc.x * s2 + bb.x;
    acc.y = acc.y * s2 + bb.y;
    acc.z = acc.z * s2 + bb.z;
    acc.w = acc.w * s2 + bb.w;

    int e = row_ptr[node];
    const int end = row_ptr[node + 1];
    for (; e + 1 < end; e += 2) {
        int s0 = col[e], s1 = col[e + 1];
        float w0 = dis[s0] * dn;
        float w1 = dis[s1] * dn;
        float4 v0 = *(const float4*)&tbuf[(long)s0 * 128 + q];
        float4 v1 = *(const float4*)&tbuf[(long)s1 * 128 + q];
        acc.x += v0.x * w0 + v1.x * w1;
        acc.y += v0.y * w0 + v1.y * w1;
        acc.z += v0.z * w0 + v1.z * w1;
        acc.w += v0.w * w0 + v1.w * w1;
    }
    if (e < end) {
        int s0 = col[e];
        float w0 = dis[s0] * dn;
        float4 v0 = *(const float4*)&tbuf[(long)s0 * 128 + q];
        acc.x += v0.x * w0;
        acc.y += v0.y * w0;
        acc.z += v0.z * w0;
        acc.w += v0.w * w0;
    }
    *(float4*)&h[(long)node * 128 + q] = acc;
}

// ---------------- pooling ----------------
__global__ void k_zero_pool(float* __restrict__ pools, float* __restrict__ counts) {
    int i = blockIdx.x * blockDim.x + threadIdx.x;
    if (i < N_GRAPHS * 128) pools[i] = 0.0f;
    if (i < N_GRAPHS) counts[i] = 0.0f;
}

__global__ void k_pool(const int* __restrict__ batch, const float* __restrict__ h,
                       float* __restrict__ pools, float* __restrict__ counts) {
    int idx = blockIdx.x * blockDim.x + threadIdx.x;  // N*32
    if (idx >= N_NODES * 32) return;
    int n = idx >> 5, qi = idx & 31;
    int q = qi << 2;
    int g = batch[n];
    float4 v = *(const float4*)&h[(long)n * 128 + q];
    float* pp = &pools[(long)g * 128 + q];
    atomicAdd(pp + 0, fmaxf(v.x, 0.f));
    atomicAdd(pp + 1, fmaxf(v.y, 0.f));
    atomicAdd(pp + 2, fmaxf(v.z, 0.f));
    atomicAdd(pp + 3, fmaxf(v.w, 0.f));
    if (qi == 0) atomicAdd(&counts[g], 1.0f);
}

// ---------------- head ----------------
__global__ __launch_bounds__(64) void k_head(const float* __restrict__ pools,
                                             const float* __restrict__ counts,
                                             const float* __restrict__ fw1, const float* __restrict__ fb1,
                                             const float* __restrict__ fw2, const float* __restrict__ fb2,
                                             float* __restrict__ out) {
    int g = blockIdx.x;
    int t = threadIdx.x;
    __shared__ float sg[128];
    __shared__ float sh[32];
    float cnt = fmaxf(counts[g], 1.0f);
    float inv = 1.0f / cnt;
    sg[t] = pools[(long)g * 128 + t] * inv;
    sg[t + 64] = pools[(long)g * 128 + 64 + t] * inv;
    __syncthreads();
    if (t < 32) {
        float a = fb1[t];
        for (int k = 0; k < 128; ++k) a += sg[k] * fw1[k * 32 + t];
        sh[t] = fmaxf(a, 0.f);
    }
    __syncthreads();
    if (t == 0) {
        float l0 = fb2[0], l1 = fb2[1];
        for (int k = 0; k < 32; ++k) {
            l0 += sh[k] * fw2[k * 2];
            l1 += sh[k] * fw2[k * 2 + 1];
        }
        float m = fmaxf(l0, l1);
        float lse = m + logf(expf(l0 - m) + expf(l1 - m));
        out[g * 2 + 0] = l0 - lse;
        out[g * 2 + 1] = l1 - lse;
    }
}

extern "C" void kernel_launch(void* const* d_in, const int* in_sizes, int n_in,
                              void* d_out, int out_size, void* d_ws, size_t ws_size,
                              hipStream_t stream) {
    const float* x  = (const float*)d_in[0];
    const int* ei   = (const int*)d_in[1];
    const int* batch = (const int*)d_in[2];
    const float* W1 = (const float*)d_in[3];
    const float* b1 = (const float*)d_in[4];
    const float* W2 = (const float*)d_in[5];
    const float* b2 = (const float*)d_in[6];
    const float* W3 = (const float*)d_in[7];
    const float* b3 = (const float*)d_in[8];
    const float* fw1 = (const float*)d_in[9];
    const float* fb1 = (const float*)d_in[10];
    const float* fw2 = (const float*)d_in[11];
    const float* fb2 = (const float*)d_in[12];
    float* out = (float*)d_out;

    const int* src = ei;
    const int* dst = ei + N_EDGES;

    // workspace layout
    char* ws = (char*)d_ws;
    int*   cnt     = (int*)ws;                                   // N ints (reused as cursor)
    float* dis     = (float*)(cnt + N_NODES);                    // N
    int*   row_ptr = (int*)(dis + N_NODES);                      // N+1
    int*   partial = row_ptr + N_NODES + 1;                      // SCAN_BLOCKS (+pad)
    int*   col     = partial + 128;                              // E
    float* buf0    = (float*)(col + N_EDGES);                    // N*128
    float* buf1    = buf0 + (long)N_NODES * 128;                 // N*128
    float* pools   = buf1 + (long)N_NODES * 128;                 // G*128
    float* cnts    = pools + (long)N_GRAPHS * 128;               // G

    const int B = 256;
    // ---- CSR build + norms ----
    k_zero_cnt<<<(N_NODES + B - 1) / B, B, 0, stream>>>(cnt);
    k_cnt<<<(N_EDGES + B - 1) / B, B, 0, stream>>>(dst, cnt);
    k_dis<<<(N_NODES + B - 1) / B, B, 0, stream>>>(cnt, dis);
    k_scan1<<<SCAN_BLOCKS, 256, 0, stream>>>(cnt, row_ptr, partial);
    k_scan2<<<1, 128, 0, stream>>>(partial, row_ptr);
    k_scan3<<<SCAN_BLOCKS, 256, 0, stream>>>(row_ptr, cnt /*cursor*/, partial);
    k_fill<<<(N_EDGES + B - 1) / B, B, 0, stream>>>(src, dst, cnt /*cursor*/, col);

    const int mmGrid = (N_NODES + 127) / 128;
    const int aggGrid = (N_NODES + 7) / 8;

    // layer 1
    k_mm<F_IN, false><<<mmGrid, 256, 0, stream>>>(x, W1, buf0, N_NODES);
    k_agg<<<aggGrid, 256, 0, stream>>>(row_ptr, col, dis, buf0, b1, buf1);
    // layer 2 (relu fused into GEMM A-read)
    k_mm<H_DIM, true><<<mmGrid, 256, 0, stream>>>(buf1, W2, buf0, N_NODES);
    k_agg<<<aggGrid, 256, 0, stream>>>(row_ptr, col, dis, buf0, b2, buf1);
    // layer 3
    k_mm<H_DIM, true><<<mmGrid, 256, 0, stream>>>(buf1, W3, buf0, N_NODES);
    k_agg<<<aggGrid, 256, 0, stream>>>(row_ptr, col, dis, buf0, b3, buf1);

    // pool (relu fused) + head
    k_zero_pool<<<(N_GRAPHS * 128 + B - 1) / B, B, 0, stream>>>(pools, cnts);
    k_pool<<<(N_NODES * 32 + B - 1) / B, B, 0, stream>>>(batch, buf1, pools, cnts);
    k_head<<<N_GRAPHS, 64, 0, stream>>>(pools, cnts, fw1, fb1, fw2, fb2, out);
}

// Round 3
// 901.890 us; speedup vs baseline: 9.7002x; 1.3171x over previous
//
#include <hip/hip_runtime.h>
#include <hip/hip_bf16.h>
#include <math.h>

#define N_NODES 100000
#define N_EDGES 1600000
#define F_IN 256
#define H_DIM 128
#define N_GRAPHS 1000
#define SCAN_CHUNK 1024
#define SCAN_BLOCKS ((N_NODES + SCAN_CHUNK - 1) / SCAN_CHUNK)  // 98

// ---------------- CSR build ----------------
__global__ void k_zero_cnt(int* __restrict__ cnt) {
    int i = blockIdx.x * blockDim.x + threadIdx.x;
    if (i < N_NODES) cnt[i] = 0;
}

__global__ void k_cnt(const int* __restrict__ dst, int* __restrict__ cnt) {
    int i = blockIdx.x * blockDim.x + threadIdx.x;
    if (i < N_EDGES) atomicAdd(&cnt[dst[i]], 1);
}

__global__ void k_dis(const int* __restrict__ cnt, float* __restrict__ dis) {
    int i = blockIdx.x * blockDim.x + threadIdx.x;
    if (i < N_NODES) dis[i] = rsqrtf((float)(cnt[i] + 1));  // +1 self-loop, always > 0
}

__global__ __launch_bounds__(256) void k_scan1(const int* __restrict__ cnt,
                                               int* __restrict__ row_ptr,
                                               int* __restrict__ partial) {
    __shared__ int s[256];
    const int t = threadIdx.x;
    const int base = blockIdx.x * SCAN_CHUNK + t * 4;
    int c0 = 0, c1 = 0, c2 = 0, c3 = 0;
    if (base + 0 < N_NODES) c0 = cnt[base + 0];
    if (base + 1 < N_NODES) c1 = cnt[base + 1];
    if (base + 2 < N_NODES) c2 = cnt[base + 2];
    if (base + 3 < N_NODES) c3 = cnt[base + 3];
    int mySum = c0 + c1 + c2 + c3;
    s[t] = mySum;
    __syncthreads();
    for (int off = 1; off < 256; off <<= 1) {
        int v = (t >= off) ? s[t - off] : 0;
        __syncthreads();
        s[t] += v;
        __syncthreads();
    }
    int excl = s[t] - mySum;
    if (base + 0 < N_NODES) row_ptr[base + 0] = excl;
    excl += c0;
    if (base + 1 < N_NODES) row_ptr[base + 1] = excl;
    excl += c1;
    if (base + 2 < N_NODES) row_ptr[base + 2] = excl;
    excl += c2;
    if (base + 3 < N_NODES) row_ptr[base + 3] = excl;
    if (t == 255) partial[blockIdx.x] = s[255];
}

__global__ __launch_bounds__(128) void k_scan2(int* __restrict__ partial, int* __restrict__ row_ptr) {
    __shared__ int s[128];
    const int t = threadIdx.x;
    int v = (t < SCAN_BLOCKS) ? partial[t] : 0;
    int mine = v;
    s[t] = v;
    __syncthreads();
    for (int off = 1; off < 128; off <<= 1) {
        int u = (t >= off) ? s[t - off] : 0;
        __syncthreads();
        s[t] += u;
        __syncthreads();
    }
    if (t < SCAN_BLOCKS) partial[t] = s[t] - mine;  // exclusive
    if (t == 0) row_ptr[N_NODES] = N_EDGES;
}

__global__ __launch_bounds__(256) void k_scan3(int* __restrict__ row_ptr, int* __restrict__ cursor,
                                               const int* __restrict__ partial) {
    const int t = threadIdx.x;
    const int base = blockIdx.x * SCAN_CHUNK + t * 4;
    int add = partial[blockIdx.x];
#pragma unroll
    for (int i = 0; i < 4; ++i) {
        int idx = base + i;
        if (idx < N_NODES) {
            int v = row_ptr[idx] + add;
            row_ptr[idx] = v;
            cursor[idx] = v;
        }
    }
}

__global__ void k_fill(const int* __restrict__ src, const int* __restrict__ dst,
                       int* __restrict__ cursor, int* __restrict__ col) {
    int e = blockIdx.x * blockDim.x + threadIdx.x;
    if (e < N_EDGES) {
        int d = dst[e];
        int pos = atomicAdd(&cursor[d], 1);
        col[pos] = src[e];
    }
}

// ---------------- GEMM: C[M,128] = (relu?)(A[M,K]) @ W[K,128], C row scaled by dis[r] ----------------
template <int K, bool RELU>
__global__ __launch_bounds__(256, 2) void k_mm(const float* __restrict__ A,
                                               const float* __restrict__ W,
                                               const float* __restrict__ scale,
                                               float* __restrict__ C, int M) {
    __shared__ float As[32 * 132];
    __shared__ float Ws[32 * 144];
    const int t = threadIdx.x;
    const int tx = t & 15;
    const int ty = t >> 4;
    const int row0 = blockIdx.x * 128;

    float acc[8][8];
#pragma unroll
    for (int i = 0; i < 8; ++i)
#pragma unroll
        for (int j = 0; j < 8; ++j) acc[i][j] = 0.0f;

    for (int k0 = 0; k0 < K; k0 += 32) {
        {
            int idx = t;
#pragma unroll
            for (int i = 0; i < 4; ++i, idx += 256) {
                int k = idx >> 5, q = idx & 31;
                int c = q << 2;
                float4 v = *(const float4*)&W[(k0 + k) * 128 + c];
                int cs = c + ((c >> 5) << 2);
                *(float4*)&Ws[k * 144 + cs] = v;
            }
        }
        {
            int idx = t;
#pragma unroll
            for (int i = 0; i < 4; ++i, idx += 256) {
                int r = idx >> 3, q = idx & 7;
                int gr = row0 + r;
                float4 v = make_float4(0.f, 0.f, 0.f, 0.f);
                if (gr < M) v = *(const float4*)&A[(long)gr * K + k0 + (q << 2)];
                if (RELU) {
                    v.x = fmaxf(v.x, 0.f); v.y = fmaxf(v.y, 0.f);
                    v.z = fmaxf(v.z, 0.f); v.w = fmaxf(v.w, 0.f);
                }
                int kb = q << 2;
                As[(kb + 0) * 132 + r] = v.x;
                As[(kb + 1) * 132 + r] = v.y;
                As[(kb + 2) * 132 + r] = v.z;
                As[(kb + 3) * 132 + r] = v.w;
            }
        }
        __syncthreads();
#pragma unroll
        for (int k = 0; k < 32; ++k) {
            const float* ap = &As[k * 132 + ty * 8];
            float4 a0 = *(const float4*)ap;
            float4 a1 = *(const float4*)(ap + 4);
            const float* wp = &Ws[k * 144 + tx * 8 + ((tx >> 2) << 2)];
            float4 w0 = *(const float4*)wp;
            float4 w1 = *(const float4*)(wp + 4);
            float av[8] = {a0.x, a0.y, a0.z, a0.w, a1.x, a1.y, a1.z, a1.w};
            float wv[8] = {w0.x, w0.y, w0.z, w0.w, w1.x, w1.y, w1.z, w1.w};
#pragma unroll
            for (int i = 0; i < 8; ++i)
#pragma unroll
                for (int j = 0; j < 8; ++j) acc[i][j] += av[i] * wv[j];
        }
        __syncthreads();
    }
#pragma unroll
    for (int i = 0; i < 8; ++i) {
        int r = row0 + ty * 8 + i;
        if (r < M) {
            float sc = scale[r];
            float4 o0 = make_float4(acc[i][0] * sc, acc[i][1] * sc, acc[i][2] * sc, acc[i][3] * sc);
            float4 o1 = make_float4(acc[i][4] * sc, acc[i][5] * sc, acc[i][6] * sc, acc[i][7] * sc);
            *(float4*)&C[(long)r * 128 + tx * 8] = o0;
            *(float4*)&C[(long)r * 128 + tx * 8 + 4] = o1;
        }
    }
}

// ---------------- CSR gather aggregation over pre-scaled t' (t' = (h@W)*dis):
//   h[n] = dis[n] * ( sum_{s in CSR[n]} t'[s] + t'[n] ) + b ----------------
__global__ __launch_bounds__(256) void k_agg(const int* __restrict__ row_ptr,
                                             const int* __restrict__ col,
                                             const float* __restrict__ dis,
                                             const float* __restrict__ tbuf,
                                             const float* __restrict__ b,
                                             float* __restrict__ h) {
    const int t = threadIdx.x;
    const int node = blockIdx.x * 8 + (t >> 5);  // 8 nodes per block, 32-lane group each
    const int lane = t & 31;
    if (node >= N_NODES) return;
    const int q = lane << 2;  // channel offset (float4)

    float4 acc = *(const float4*)&tbuf[(long)node * 128 + q];  // self term t'[n]

    int e = row_ptr[node];
    const int end = row_ptr[node + 1];
    for (; e + 3 < end; e += 4) {
        int s0 = col[e], s1 = col[e + 1], s2 = col[e + 2], s3 = col[e + 3];
        float4 v0 = *(const float4*)&tbuf[(long)s0 * 128 + q];
        float4 v1 = *(const float4*)&tbuf[(long)s1 * 128 + q];
        float4 v2 = *(const float4*)&tbuf[(long)s2 * 128 + q];
        float4 v3 = *(const float4*)&tbuf[(long)s3 * 128 + q];
        acc.x += (v0.x + v1.x) + (v2.x + v3.x);
        acc.y += (v0.y + v1.y) + (v2.y + v3.y);
        acc.z += (v0.z + v1.z) + (v2.z + v3.z);
        acc.w += (v0.w + v1.w) + (v2.w + v3.w);
    }
    for (; e < end; ++e) {
        int s0 = col[e];
        float4 v0 = *(const float4*)&tbuf[(long)s0 * 128 + q];
        acc.x += v0.x; acc.y += v0.y; acc.z += v0.z; acc.w += v0.w;
    }
    const float dn = dis[node];
    float4 bb = *(const float4*)&b[q];
    float4 o;
    o.x = acc.x * dn + bb.x;
    o.y = acc.y * dn + bb.y;
    o.z = acc.z * dn + bb.z;
    o.w = acc.w * dn + bb.w;
    *(float4*)&h[(long)node * 128 + q] = o;
}

// ---------------- graph segment bounds (batch is sorted) ----------------
__global__ void k_bounds(const int* __restrict__ batch, int* __restrict__ bounds) {
    int g = blockIdx.x * blockDim.x + threadIdx.x;
    if (g > N_GRAPHS) return;
    int lo = 0, hi = N_NODES;
    while (lo < hi) {
        int mid = (lo + hi) >> 1;
        if (batch[mid] < g) lo = mid + 1; else hi = mid;
    }
    bounds[g] = lo;  // first index with batch[idx] >= g
}

// ---------------- fused pool (mean of relu(h) over segment) + MLP head ----------------
__global__ __launch_bounds__(128) void k_pool_head(const int* __restrict__ bounds,
                                                   const float* __restrict__ h,
                                                   const float* __restrict__ fw1, const float* __restrict__ fb1,
                                                   const float* __restrict__ fw2, const float* __restrict__ fb2,
                                                   float* __restrict__ out) {
    const int g = blockIdx.x;
    const int t = threadIdx.x;
    const int s = bounds[g], e = bounds[g + 1];
    float sum = 0.0f;
    int n = s;
    for (; n + 1 < e; n += 2) {
        sum += fmaxf(h[(long)n * 128 + t], 0.0f);
        sum += fmaxf(h[(long)(n + 1) * 128 + t], 0.0f);
    }
    if (n < e) sum += fmaxf(h[(long)n * 128 + t], 0.0f);

    __shared__ float sg[128];
    __shared__ float sh[32];
    float inv = 1.0f / fmaxf((float)(e - s), 1.0f);
    sg[t] = sum * inv;
    __syncthreads();
    if (t < 32) {
        float a = fb1[t];
#pragma unroll 8
        for (int k = 0; k < 128; ++k) a += sg[k] * fw1[k * 32 + t];
        sh[t] = fmaxf(a, 0.0f);
    }
    __syncthreads();
    if (t == 0) {
        float l0 = fb2[0], l1 = fb2[1];
        for (int k = 0; k < 32; ++k) {
            l0 += sh[k] * fw2[k * 2];
            l1 += sh[k] * fw2[k * 2 + 1];
        }
        float m = fmaxf(l0, l1);
        float lse = m + logf(expf(l0 - m) + expf(l1 - m));
        out[g * 2 + 0] = l0 - lse;
        out[g * 2 + 1] = l1 - lse;
    }
}

extern "C" void kernel_launch(void* const* d_in, const int* in_sizes, int n_in,
                              void* d_out, int out_size, void* d_ws, size_t ws_size,
                              hipStream_t stream) {
    const float* x  = (const float*)d_in[0];
    const int* ei   = (const int*)d_in[1];
    const int* batch = (const int*)d_in[2];
    const float* W1 = (const float*)d_in[3];
    const float* b1 = (const float*)d_in[4];
    const float* W2 = (const float*)d_in[5];
    const float* b2 = (const float*)d_in[6];
    const float* W3 = (const float*)d_in[7];
    const float* b3 = (const float*)d_in[8];
    const float* fw1 = (const float*)d_in[9];
    const float* fb1 = (const float*)d_in[10];
    const float* fw2 = (const float*)d_in[11];
    const float* fb2 = (const float*)d_in[12];
    float* out = (float*)d_out;

    const int* src = ei;
    const int* dst = ei + N_EDGES;

    // workspace layout
    char* ws = (char*)d_ws;
    int*   cnt     = (int*)ws;                                   // N ints (reused as cursor)
    float* dis     = (float*)(cnt + N_NODES);                    // N
    int*   row_ptr = (int*)(dis + N_NODES);                      // N+1
    int*   partial = row_ptr + N_NODES + 1;                      // SCAN_BLOCKS (+pad)
    int*   bounds  = partial + 128;                              // G+1
    int*   col     = bounds + N_GRAPHS + 8;                      // E
    float* buf0    = (float*)(col + N_EDGES);                    // N*128
    float* buf1    = buf0 + (long)N_NODES * 128;                 // N*128

    const int B = 256;
    // ---- CSR build + norms + segment bounds ----
    k_zero_cnt<<<(N_NODES + B - 1) / B, B, 0, stream>>>(cnt);
    k_cnt<<<(N_EDGES + B - 1) / B, B, 0, stream>>>(dst, cnt);
    k_dis<<<(N_NODES + B - 1) / B, B, 0, stream>>>(cnt, dis);
    k_scan1<<<SCAN_BLOCKS, 256, 0, stream>>>(cnt, row_ptr, partial);
    k_scan2<<<1, 128, 0, stream>>>(partial, row_ptr);
    k_scan3<<<SCAN_BLOCKS, 256, 0, stream>>>(row_ptr, cnt /*cursor*/, partial);
    k_fill<<<(N_EDGES + B - 1) / B, B, 0, stream>>>(src, dst, cnt /*cursor*/, col);
    k_bounds<<<(N_GRAPHS + 1 + 255) / 256, 256, 0, stream>>>(batch, bounds);

    const int mmGrid = (N_NODES + 127) / 128;
    const int aggGrid = (N_NODES + 7) / 8;

    // layer 1
    k_mm<F_IN, false><<<mmGrid, 256, 0, stream>>>(x, W1, dis, buf0, N_NODES);
    k_agg<<<aggGrid, 256, 0, stream>>>(row_ptr, col, dis, buf0, b1, buf1);
    // layer 2 (relu fused into GEMM A-read)
    k_mm<H_DIM, true><<<mmGrid, 256, 0, stream>>>(buf1, W2, dis, buf0, N_NODES);
    k_agg<<<aggGrid, 256, 0, stream>>>(row_ptr, col, dis, buf0, b2, buf1);
    // layer 3
    k_mm<H_DIM, true><<<mmGrid, 256, 0, stream>>>(buf1, W3, dis, buf0, N_NODES);
    k_agg<<<aggGrid, 256, 0, stream>>>(row_ptr, col, dis, buf0, b3, buf1);

    // fused pool + head (batch sorted -> contiguous segments)
    k_pool_head<<<N_GRAPHS, 128, 0, stream>>>(bounds, buf1, fw1, fb1, fw2, fb2, out);
}

// Round 4
// 710.419 us; speedup vs baseline: 12.3145x; 1.2695x over previous
//
#include <hip/hip_runtime.h>
#include <hip/hip_bf16.h>
#include <math.h>

#define N_NODES 100000
#define N_EDGES 1600000
#define F_IN 256
#define H_DIM 128
#define N_GRAPHS 1000
#define SCAN_CHUNK 1024
#define SCAN_BLOCKS ((N_NODES + SCAN_CHUNK - 1) / SCAN_CHUNK)  // 98

typedef unsigned short bfu;  // bf16 bit pattern

__device__ __forceinline__ float b2f(bfu u) {
    union { unsigned int i; float f; } v;
    v.i = (unsigned int)u << 16;
    return v.f;
}
__device__ __forceinline__ bfu f2b(float f) {
    __hip_bfloat16 h = __float2bfloat16(f);  // RNE
    return *reinterpret_cast<bfu*>(&h);
}

// ---------------- CSR build ----------------
__global__ void k_zero_cnt(int* __restrict__ cnt) {
    int i = blockIdx.x * blockDim.x + threadIdx.x;
    if (i < N_NODES) cnt[i] = 0;
}

__global__ void k_cnt(const int* __restrict__ dst, int* __restrict__ cnt) {
    int i = blockIdx.x * blockDim.x + threadIdx.x;
    if (i < N_EDGES) atomicAdd(&cnt[dst[i]], 1);
}

__global__ void k_dis(const int* __restrict__ cnt, float* __restrict__ dis) {
    int i = blockIdx.x * blockDim.x + threadIdx.x;
    if (i < N_NODES) dis[i] = rsqrtf((float)(cnt[i] + 1));  // +1 self-loop
}

__global__ __launch_bounds__(256) void k_scan1(const int* __restrict__ cnt,
                                               int* __restrict__ row_ptr,
                                               int* __restrict__ partial) {
    __shared__ int s[256];
    const int t = threadIdx.x;
    const int base = blockIdx.x * SCAN_CHUNK + t * 4;
    int c0 = 0, c1 = 0, c2 = 0, c3 = 0;
    if (base + 0 < N_NODES) c0 = cnt[base + 0];
    if (base + 1 < N_NODES) c1 = cnt[base + 1];
    if (base + 2 < N_NODES) c2 = cnt[base + 2];
    if (base + 3 < N_NODES) c3 = cnt[base + 3];
    int mySum = c0 + c1 + c2 + c3;
    s[t] = mySum;
    __syncthreads();
    for (int off = 1; off < 256; off <<= 1) {
        int v = (t >= off) ? s[t - off] : 0;
        __syncthreads();
        s[t] += v;
        __syncthreads();
    }
    int excl = s[t] - mySum;
    if (base + 0 < N_NODES) row_ptr[base + 0] = excl;
    excl += c0;
    if (base + 1 < N_NODES) row_ptr[base + 1] = excl;
    excl += c1;
    if (base + 2 < N_NODES) row_ptr[base + 2] = excl;
    excl += c2;
    if (base + 3 < N_NODES) row_ptr[base + 3] = excl;
    if (t == 255) partial[blockIdx.x] = s[255];
}

__global__ __launch_bounds__(128) void k_scan2(int* __restrict__ partial, int* __restrict__ row_ptr) {
    __shared__ int s[128];
    const int t = threadIdx.x;
    int v = (t < SCAN_BLOCKS) ? partial[t] : 0;
    int mine = v;
    s[t] = v;
    __syncthreads();
    for (int off = 1; off < 128; off <<= 1) {
        int u = (t >= off) ? s[t - off] : 0;
        __syncthreads();
        s[t] += u;
        __syncthreads();
    }
    if (t < SCAN_BLOCKS) partial[t] = s[t] - mine;  // exclusive
    if (t == 0) row_ptr[N_NODES] = N_EDGES;
}

__global__ __launch_bounds__(256) void k_scan3(int* __restrict__ row_ptr, int* __restrict__ cursor,
                                               const int* __restrict__ partial) {
    const int t = threadIdx.x;
    const int base = blockIdx.x * SCAN_CHUNK + t * 4;
    int add = partial[blockIdx.x];
#pragma unroll
    for (int i = 0; i < 4; ++i) {
        int idx = base + i;
        if (idx < N_NODES) {
            int v = row_ptr[idx] + add;
            row_ptr[idx] = v;
            cursor[idx] = v;
        }
    }
}

__global__ void k_fill(const int* __restrict__ src, const int* __restrict__ dst,
                       int* __restrict__ cursor, int* __restrict__ col) {
    int e = blockIdx.x * blockDim.x + threadIdx.x;
    if (e < N_EDGES) {
        int d = dst[e];
        int pos = atomicAdd(&cursor[d], 1);
        col[pos] = src[e];
    }
}

// ---------------- GEMM: C[M,128](bf16) = A[M,K] @ W[K,128], row r scaled by dis[r] ----------------
// AT = float (layer 1, x) or bfu (layers 2/3, h already relu'd). Math fp32.
template <int K, typename AT>
__global__ __launch_bounds__(256, 2) void k_mm(const AT* __restrict__ A,
                                               const float* __restrict__ W,
                                               const float* __restrict__ scale,
                                               bfu* __restrict__ C, int M) {
    __shared__ float As[32 * 132];
    __shared__ float Ws[32 * 144];
    const int t = threadIdx.x;
    const int tx = t & 15;
    const int ty = t >> 4;
    const int row0 = blockIdx.x * 128;

    float acc[8][8];
#pragma unroll
    for (int i = 0; i < 8; ++i)
#pragma unroll
        for (int j = 0; j < 8; ++j) acc[i][j] = 0.0f;

    for (int k0 = 0; k0 < K; k0 += 32) {
        {
            int idx = t;
#pragma unroll
            for (int i = 0; i < 4; ++i, idx += 256) {
                int k = idx >> 5, q = idx & 31;
                int c = q << 2;
                float4 v = *(const float4*)&W[(k0 + k) * 128 + c];
                int cs = c + ((c >> 5) << 2);
                *(float4*)&Ws[k * 144 + cs] = v;
            }
        }
        {
            int idx = t;
#pragma unroll
            for (int i = 0; i < 4; ++i, idx += 256) {
                int r = idx >> 3, q = idx & 7;
                int gr = row0 + r;
                float f0 = 0.f, f1 = 0.f, f2 = 0.f, f3 = 0.f;
                if (gr < M) {
                    if constexpr (sizeof(AT) == 4) {
                        float4 v = *(const float4*)&A[(long)gr * K + k0 + (q << 2)];
                        f0 = v.x; f1 = v.y; f2 = v.z; f3 = v.w;
                    } else {
                        uint2 v = *(const uint2*)&A[(long)gr * K + k0 + (q << 2)];
                        f0 = b2f((bfu)(v.x & 0xffff));
                        f1 = b2f((bfu)(v.x >> 16));
                        f2 = b2f((bfu)(v.y & 0xffff));
                        f3 = b2f((bfu)(v.y >> 16));
                    }
                }
                int kb = q << 2;
                As[(kb + 0) * 132 + r] = f0;
                As[(kb + 1) * 132 + r] = f1;
                As[(kb + 2) * 132 + r] = f2;
                As[(kb + 3) * 132 + r] = f3;
            }
        }
        __syncthreads();
#pragma unroll
        for (int k = 0; k < 32; ++k) {
            const float* ap = &As[k * 132 + ty * 8];
            float4 a0 = *(const float4*)ap;
            float4 a1 = *(const float4*)(ap + 4);
            const float* wp = &Ws[k * 144 + tx * 8 + ((tx >> 2) << 2)];
            float4 w0 = *(const float4*)wp;
            float4 w1 = *(const float4*)(wp + 4);
            float av[8] = {a0.x, a0.y, a0.z, a0.w, a1.x, a1.y, a1.z, a1.w};
            float wv[8] = {w0.x, w0.y, w0.z, w0.w, w1.x, w1.y, w1.z, w1.w};
#pragma unroll
            for (int i = 0; i < 8; ++i)
#pragma unroll
                for (int j = 0; j < 8; ++j) acc[i][j] += av[i] * wv[j];
        }
        __syncthreads();
    }
#pragma unroll
    for (int i = 0; i < 8; ++i) {
        int r = row0 + ty * 8 + i;
        if (r < M) {
            float sc = scale[r];
            uint4 pk;
            pk.x = (unsigned)f2b(acc[i][0] * sc) | ((unsigned)f2b(acc[i][1] * sc) << 16);
            pk.y = (unsigned)f2b(acc[i][2] * sc) | ((unsigned)f2b(acc[i][3] * sc) << 16);
            pk.z = (unsigned)f2b(acc[i][4] * sc) | ((unsigned)f2b(acc[i][5] * sc) << 16);
            pk.w = (unsigned)f2b(acc[i][6] * sc) | ((unsigned)f2b(acc[i][7] * sc) << 16);
            *(uint4*)&C[(long)r * 128 + tx * 8] = pk;
        }
    }
}

// ---------------- CSR gather aggregation (bf16 storage, fp32 accum):
//   h[n] = relu( dis[n] * ( sum_{s in CSR[n]} t'[s] + t'[n] ) + b )  stored bf16 ----------------
__global__ __launch_bounds__(256) void k_agg(const int* __restrict__ row_ptr,
                                             const int* __restrict__ col,
                                             const float* __restrict__ dis,
                                             const bfu* __restrict__ tbuf,
                                             const float* __restrict__ b,
                                             bfu* __restrict__ h) {
    const int t = threadIdx.x;
    const int node = blockIdx.x * 8 + (t >> 5);  // 8 nodes/block, 32-lane group each
    const int lane = t & 31;
    if (node >= N_NODES) return;
    const int q = lane << 2;  // 4 channels per lane

    uint2 sv = *(const uint2*)&tbuf[(long)node * 128 + q];  // self term t'[n]
    float a0 = b2f((bfu)(sv.x & 0xffff));
    float a1 = b2f((bfu)(sv.x >> 16));
    float a2 = b2f((bfu)(sv.y & 0xffff));
    float a3 = b2f((bfu)(sv.y >> 16));

    int e = row_ptr[node];
    const int end = row_ptr[node + 1];
    for (; e + 3 < end; e += 4) {
        int s0 = col[e], s1 = col[e + 1], s2 = col[e + 2], s3 = col[e + 3];
        uint2 v0 = *(const uint2*)&tbuf[(long)s0 * 128 + q];
        uint2 v1 = *(const uint2*)&tbuf[(long)s1 * 128 + q];
        uint2 v2 = *(const uint2*)&tbuf[(long)s2 * 128 + q];
        uint2 v3 = *(const uint2*)&tbuf[(long)s3 * 128 + q];
        a0 += (b2f((bfu)(v0.x & 0xffff)) + b2f((bfu)(v1.x & 0xffff))) +
              (b2f((bfu)(v2.x & 0xffff)) + b2f((bfu)(v3.x & 0xffff)));
        a1 += (b2f((bfu)(v0.x >> 16)) + b2f((bfu)(v1.x >> 16))) +
              (b2f((bfu)(v2.x >> 16)) + b2f((bfu)(v3.x >> 16)));
        a2 += (b2f((bfu)(v0.y & 0xffff)) + b2f((bfu)(v1.y & 0xffff))) +
              (b2f((bfu)(v2.y & 0xffff)) + b2f((bfu)(v3.y & 0xffff)));
        a3 += (b2f((bfu)(v0.y >> 16)) + b2f((bfu)(v1.y >> 16))) +
              (b2f((bfu)(v2.y >> 16)) + b2f((bfu)(v3.y >> 16)));
    }
    for (; e < end; ++e) {
        int s0 = col[e];
        uint2 v0 = *(const uint2*)&tbuf[(long)s0 * 128 + q];
        a0 += b2f((bfu)(v0.x & 0xffff));
        a1 += b2f((bfu)(v0.x >> 16));
        a2 += b2f((bfu)(v0.y & 0xffff));
        a3 += b2f((bfu)(v0.y >> 16));
    }
    const float dn = dis[node];
    float4 bb = *(const float4*)&b[q];
    float o0 = fmaxf(a0 * dn + bb.x, 0.0f);
    float o1 = fmaxf(a1 * dn + bb.y, 0.0f);
    float o2 = fmaxf(a2 * dn + bb.z, 0.0f);
    float o3 = fmaxf(a3 * dn + bb.w, 0.0f);
    uint2 pk;
    pk.x = (unsigned)f2b(o0) | ((unsigned)f2b(o1) << 16);
    pk.y = (unsigned)f2b(o2) | ((unsigned)f2b(o3) << 16);
    *(uint2*)&h[(long)node * 128 + q] = pk;
}

// ---------------- graph segment bounds (batch is sorted) ----------------
__global__ void k_bounds(const int* __restrict__ batch, int* __restrict__ bounds) {
    int g = blockIdx.x * blockDim.x + threadIdx.x;
    if (g > N_GRAPHS) return;
    int lo = 0, hi = N_NODES;
    while (lo < hi) {
        int mid = (lo + hi) >> 1;
        if (batch[mid] < g) lo = mid + 1; else hi = mid;
    }
    bounds[g] = lo;
}

// ---------------- fused pool (mean over segment; h already relu'd) + MLP head ----------------
__global__ __launch_bounds__(128) void k_pool_head(const int* __restrict__ bounds,
                                                   const bfu* __restrict__ h,
                                                   const float* __restrict__ fw1, const float* __restrict__ fb1,
                                                   const float* __restrict__ fw2, const float* __restrict__ fb2,
                                                   float* __restrict__ out) {
    const int g = blockIdx.x;
    const int t = threadIdx.x;
    const int s = bounds[g], e = bounds[g + 1];
    float sum = 0.0f;
    int n = s;
    for (; n + 1 < e; n += 2) {
        sum += b2f(h[(long)n * 128 + t]);
        sum += b2f(h[(long)(n + 1) * 128 + t]);
    }
    if (n < e) sum += b2f(h[(long)n * 128 + t]);

    __shared__ float sg[128];
    __shared__ float sh[32];
    float inv = 1.0f / fmaxf((float)(e - s), 1.0f);
    sg[t] = sum * inv;
    __syncthreads();
    if (t < 32) {
        float a = fb1[t];
#pragma unroll 8
        for (int k = 0; k < 128; ++k) a += sg[k] * fw1[k * 32 + t];
        sh[t] = fmaxf(a, 0.0f);
    }
    __syncthreads();
    if (t == 0) {
        float l0 = fb2[0], l1 = fb2[1];
        for (int k = 0; k < 32; ++k) {
            l0 += sh[k] * fw2[k * 2];
            l1 += sh[k] * fw2[k * 2 + 1];
        }
        float m = fmaxf(l0, l1);
        float lse = m + logf(expf(l0 - m) + expf(l1 - m));
        out[g * 2 + 0] = l0 - lse;
        out[g * 2 + 1] = l1 - lse;
    }
}

extern "C" void kernel_launch(void* const* d_in, const int* in_sizes, int n_in,
                              void* d_out, int out_size, void* d_ws, size_t ws_size,
                              hipStream_t stream) {
    const float* x  = (const float*)d_in[0];
    const int* ei   = (const int*)d_in[1];
    const int* batch = (const int*)d_in[2];
    const float* W1 = (const float*)d_in[3];
    const float* b1 = (const float*)d_in[4];
    const float* W2 = (const float*)d_in[5];
    const float* b2 = (const float*)d_in[6];
    const float* W3 = (const float*)d_in[7];
    const float* b3 = (const float*)d_in[8];
    const float* fw1 = (const float*)d_in[9];
    const float* fb1 = (const float*)d_in[10];
    const float* fw2 = (const float*)d_in[11];
    const float* fb2 = (const float*)d_in[12];
    float* out = (float*)d_out;

    const int* src = ei;
    const int* dst = ei + N_EDGES;

    // workspace layout
    char* ws = (char*)d_ws;
    int*   cnt     = (int*)ws;                                   // N ints (reused as cursor)
    float* dis     = (float*)(cnt + N_NODES);                    // N
    int*   row_ptr = (int*)(dis + N_NODES);                      // N+1
    int*   partial = row_ptr + N_NODES + 1;                      // SCAN_BLOCKS (+pad)
    int*   bounds  = partial + 128;                              // G+1
    int*   col     = bounds + N_GRAPHS + 8;                      // E
    bfu*   buf0    = (bfu*)(col + N_EDGES);                      // N*128 bf16 (t')
    bfu*   buf1    = buf0 + (long)N_NODES * 128;                 // N*128 bf16 (h, post-relu)

    const int B = 256;
    // ---- CSR build + norms + segment bounds ----
    k_zero_cnt<<<(N_NODES + B - 1) / B, B, 0, stream>>>(cnt);
    k_cnt<<<(N_EDGES + B - 1) / B, B, 0, stream>>>(dst, cnt);
    k_dis<<<(N_NODES + B - 1) / B, B, 0, stream>>>(cnt, dis);
    k_scan1<<<SCAN_BLOCKS, 256, 0, stream>>>(cnt, row_ptr, partial);
    k_scan2<<<1, 128, 0, stream>>>(partial, row_ptr);
    k_scan3<<<SCAN_BLOCKS, 256, 0, stream>>>(row_ptr, cnt /*cursor*/, partial);
    k_fill<<<(N_EDGES + B - 1) / B, B, 0, stream>>>(src, dst, cnt /*cursor*/, col);
    k_bounds<<<(N_GRAPHS + 1 + 255) / 256, 256, 0, stream>>>(batch, bounds);

    const int mmGrid = (N_NODES + 127) / 128;
    const int aggGrid = (N_NODES + 7) / 8;

    // layer 1 (A = x fp32)
    k_mm<F_IN, float><<<mmGrid, 256, 0, stream>>>(x, W1, dis, buf0, N_NODES);
    k_agg<<<aggGrid, 256, 0, stream>>>(row_ptr, col, dis, buf0, b1, buf1);
    // layer 2 (A = h bf16, already relu'd)
    k_mm<H_DIM, bfu><<<mmGrid, 256, 0, stream>>>(buf1, W2, dis, buf0, N_NODES);
    k_agg<<<aggGrid, 256, 0, stream>>>(row_ptr, col, dis, buf0, b2, buf1);
    // layer 3
    k_mm<H_DIM, bfu><<<mmGrid, 256, 0, stream>>>(buf1, W3, dis, buf0, N_NODES);
    k_agg<<<aggGrid, 256, 0, stream>>>(row_ptr, col, dis, buf0, b3, buf1);

    // fused pool + head
    k_pool_head<<<N_GRAPHS, 128, 0, stream>>>(bounds, buf1, fw1, fb1, fw2, fb2, out);
}

// Round 5
// 580.288 us; speedup vs baseline: 15.0761x; 1.2243x over previous
//
#include <hip/hip_runtime.h>
#include <hip/hip_bf16.h>
#include <math.h>

#define N_NODES 100000
#define N_EDGES 1600000
#define F_IN 256
#define H_DIM 128
#define N_GRAPHS 1000
#define SCAN_CHUNK 1024
#define SCAN_BLOCKS ((N_NODES + SCAN_CHUNK - 1) / SCAN_CHUNK)  // 98

typedef unsigned short bfu;  // bf16 bit pattern
typedef short short8 __attribute__((ext_vector_type(8)));   // 8 bf16 = 4 VGPR
typedef float f32x4 __attribute__((ext_vector_type(4)));    // MFMA accum

__device__ __forceinline__ float b2f(bfu u) {
    union { unsigned int i; float f; } v;
    v.i = (unsigned int)u << 16;
    return v.f;
}
__device__ __forceinline__ bfu f2b(float f) {
    __hip_bfloat16 h = __float2bfloat16(f);  // RNE
    return *reinterpret_cast<bfu*>(&h);
}

// ---------------- CSR build ----------------
__global__ void k_zero_cnt(int* __restrict__ cnt) {
    int i = blockIdx.x * blockDim.x + threadIdx.x;
    if (i < N_NODES) cnt[i] = 0;
}

__global__ void k_cnt(const int* __restrict__ dst, int* __restrict__ cnt) {
    int i = blockIdx.x * blockDim.x + threadIdx.x;
    if (i < N_EDGES) atomicAdd(&cnt[dst[i]], 1);
}

__global__ void k_dis(const int* __restrict__ cnt, float* __restrict__ dis) {
    int i = blockIdx.x * blockDim.x + threadIdx.x;
    if (i < N_NODES) dis[i] = rsqrtf((float)(cnt[i] + 1));  // +1 self-loop
}

__global__ __launch_bounds__(256) void k_scan1(const int* __restrict__ cnt,
                                               int* __restrict__ row_ptr,
                                               int* __restrict__ partial) {
    __shared__ int s[256];
    const int t = threadIdx.x;
    const int base = blockIdx.x * SCAN_CHUNK + t * 4;
    int c0 = 0, c1 = 0, c2 = 0, c3 = 0;
    if (base + 0 < N_NODES) c0 = cnt[base + 0];
    if (base + 1 < N_NODES) c1 = cnt[base + 1];
    if (base + 2 < N_NODES) c2 = cnt[base + 2];
    if (base + 3 < N_NODES) c3 = cnt[base + 3];
    int mySum = c0 + c1 + c2 + c3;
    s[t] = mySum;
    __syncthreads();
    for (int off = 1; off < 256; off <<= 1) {
        int v = (t >= off) ? s[t - off] : 0;
        __syncthreads();
        s[t] += v;
        __syncthreads();
    }
    int excl = s[t] - mySum;
    if (base + 0 < N_NODES) row_ptr[base + 0] = excl;
    excl += c0;
    if (base + 1 < N_NODES) row_ptr[base + 1] = excl;
    excl += c1;
    if (base + 2 < N_NODES) row_ptr[base + 2] = excl;
    excl += c2;
    if (base + 3 < N_NODES) row_ptr[base + 3] = excl;
    if (t == 255) partial[blockIdx.x] = s[255];
}

__global__ __launch_bounds__(128) void k_scan2(int* __restrict__ partial, int* __restrict__ row_ptr) {
    __shared__ int s[128];
    const int t = threadIdx.x;
    int v = (t < SCAN_BLOCKS) ? partial[t] : 0;
    int mine = v;
    s[t] = v;
    __syncthreads();
    for (int off = 1; off < 128; off <<= 1) {
        int u = (t >= off) ? s[t - off] : 0;
        __syncthreads();
        s[t] += u;
        __syncthreads();
    }
    if (t < SCAN_BLOCKS) partial[t] = s[t] - mine;  // exclusive
    if (t == 0) row_ptr[N_NODES] = N_EDGES;
}

__global__ __launch_bounds__(256) void k_scan3(int* __restrict__ row_ptr, int* __restrict__ cursor,
                                               const int* __restrict__ partial) {
    const int t = threadIdx.x;
    const int base = blockIdx.x * SCAN_CHUNK + t * 4;
    int add = partial[blockIdx.x];
#pragma unroll
    for (int i = 0; i < 4; ++i) {
        int idx = base + i;
        if (idx < N_NODES) {
            int v = row_ptr[idx] + add;
            row_ptr[idx] = v;
            cursor[idx] = v;
        }
    }
}

__global__ void k_fill(const int* __restrict__ src, const int* __restrict__ dst,
                       int* __restrict__ cursor, int* __restrict__ col) {
    int e = blockIdx.x * blockDim.x + threadIdx.x;
    if (e < N_EDGES) {
        int d = dst[e];
        int pos = atomicAdd(&cursor[d], 1);
        col[pos] = src[e];
    }
}

// ---------------- W pre-pack: fp32 W[K][128] -> bf16 B-fragments ----------------
// Wp[ks][nf][lane][j] = W[ks*32 + (lane>>4)*8 + j][nf*16 + (lane&15)]
__global__ void k_wpack(const float* __restrict__ W, bfu* __restrict__ Wp, int K) {
    int u = blockIdx.x * 256 + threadIdx.x;
    int total = (K / 32) * 8 * 64;
    if (u >= total) return;
    int lane = u & 63;
    int nf = (u >> 6) & 7;
    int ks = u >> 9;
    int k = ks * 32 + (lane >> 4) * 8;
    int n = nf * 16 + (lane & 15);
    bfu o[8];
#pragma unroll
    for (int j = 0; j < 8; ++j) o[j] = f2b(W[(k + j) * 128 + n]);
    uint4 pk;
    pk.x = (unsigned)o[0] | ((unsigned)o[1] << 16);
    pk.y = (unsigned)o[2] | ((unsigned)o[3] << 16);
    pk.z = (unsigned)o[4] | ((unsigned)o[5] << 16);
    pk.w = (unsigned)o[6] | ((unsigned)o[7] << 16);
    *(uint4*)&Wp[u * 8] = pk;
}

// ---------------- MFMA GEMM: C[M,128](bf16) = A[M,K] @ W, row r scaled by dis[r] ----------------
// 256 threads = 4 waves; tile 128 rows; wave w owns rows w*32..w*32+31, all 128 cols.
// Swapped operands: acc[nf][mf] = mfma(Wfrag[nf], Afrag[mf], acc) -> lane holds
// C[row = wbase + mf*16 + (l&15)][n = nf*16 + (l>>4)*4 + reg] (4 consecutive n -> 8B store).
template <int K, typename AT>
__global__ __launch_bounds__(256) void k_mm_mfma(const AT* __restrict__ A,
                                                 const bfu* __restrict__ Wp,
                                                 const float* __restrict__ dis,
                                                 bfu* __restrict__ C, int M) {
    __shared__ bfu As[128 * 40];  // 128 rows x 32 bf16, pitch 40 bfu (80 B) => 2-way-only bank alias
    const int t = threadIdx.x;
    const int w = t >> 6;
    const int l = t & 63;
    const int row0 = blockIdx.x * 128;
    const int l15 = l & 15;
    const int lhi = l >> 4;

    f32x4 acc[8][2];
#pragma unroll
    for (int nf = 0; nf < 8; ++nf)
#pragma unroll
        for (int mf = 0; mf < 2; ++mf) acc[nf][mf] = (f32x4)0.0f;

    for (int ks = 0; ks < K / 32; ++ks) {
        const int k0 = ks * 32;
        // ---- stage A slab (128 rows x 32 k, bf16) ----
        if constexpr (sizeof(AT) == 4) {
            // fp32 input: convert while staging
#pragma unroll
            for (int i = 0; i < 4; ++i) {
                int idx = t + i * 256;          // 1024 chunks of 4 floats
                int row = idx >> 3, slot = idx & 7;
                int gr = row0 + row;
                float4 v = make_float4(0.f, 0.f, 0.f, 0.f);
                if (gr < M) v = *(const float4*)&A[(long)gr * K + k0 + slot * 4];
                uint2 pk;
                pk.x = (unsigned)f2b(v.x) | ((unsigned)f2b(v.y) << 16);
                pk.y = (unsigned)f2b(v.z) | ((unsigned)f2b(v.w) << 16);
                *(uint2*)&As[row * 40 + slot * 4] = pk;
            }
        } else {
#pragma unroll
            for (int i = 0; i < 2; ++i) {
                int idx = t + i * 256;          // 512 chunks of 8 bf16
                int row = idx >> 2, slot = idx & 3;
                int gr = row0 + row;
                uint4 v = make_uint4(0u, 0u, 0u, 0u);
                if (gr < M) v = *(const uint4*)&A[(long)gr * K + k0 + slot * 8];
                *(uint4*)&As[row * 40 + slot * 8] = v;
            }
        }
        __syncthreads();
        // ---- fragments ----
        short8 a0 = *(const short8*)&As[(w * 32 + l15) * 40 + lhi * 8];
        short8 a1 = *(const short8*)&As[(w * 32 + 16 + l15) * 40 + lhi * 8];
        const bfu* wp = Wp + ((long)(ks * 8) * 64 + l) * 8;
#pragma unroll
        for (int nf = 0; nf < 8; ++nf) {
            short8 wf = *(const short8*)(wp + (long)nf * 64 * 8);
            acc[nf][0] = __builtin_amdgcn_mfma_f32_16x16x32_bf16(wf, a0, acc[nf][0], 0, 0, 0);
            acc[nf][1] = __builtin_amdgcn_mfma_f32_16x16x32_bf16(wf, a1, acc[nf][1], 0, 0, 0);
        }
        __syncthreads();
    }
    // ---- epilogue: scale by dis[row], pack 4 bf16 -> 8B store ----
#pragma unroll
    for (int mf = 0; mf < 2; ++mf) {
        int row = row0 + w * 32 + mf * 16 + l15;
        if (row < M) {
            float sc = dis[row];
            int nb0 = lhi * 4;
#pragma unroll
            for (int nf = 0; nf < 8; ++nf) {
                f32x4 ac = acc[nf][mf];
                uint2 pk;
                pk.x = (unsigned)f2b(ac[0] * sc) | ((unsigned)f2b(ac[1] * sc) << 16);
                pk.y = (unsigned)f2b(ac[2] * sc) | ((unsigned)f2b(ac[3] * sc) << 16);
                *(uint2*)&C[(long)row * 128 + nf * 16 + nb0] = pk;
            }
        }
    }
}

// ---------------- CSR gather aggregation (bf16 storage, fp32 accum) ----------------
__global__ __launch_bounds__(256) void k_agg(const int* __restrict__ row_ptr,
                                             const int* __restrict__ col,
                                             const float* __restrict__ dis,
                                             const bfu* __restrict__ tbuf,
                                             const float* __restrict__ b,
                                             bfu* __restrict__ h) {
    const int t = threadIdx.x;
    const int node = blockIdx.x * 8 + (t >> 5);
    const int lane = t & 31;
    if (node >= N_NODES) return;
    const int q = lane << 2;

    uint2 sv = *(const uint2*)&tbuf[(long)node * 128 + q];
    float a0 = b2f((bfu)(sv.x & 0xffff));
    float a1 = b2f((bfu)(sv.x >> 16));
    float a2 = b2f((bfu)(sv.y & 0xffff));
    float a3 = b2f((bfu)(sv.y >> 16));

    int e = row_ptr[node];
    const int end = row_ptr[node + 1];
    for (; e + 3 < end; e += 4) {
        int s0 = col[e], s1 = col[e + 1], s2 = col[e + 2], s3 = col[e + 3];
        uint2 v0 = *(const uint2*)&tbuf[(long)s0 * 128 + q];
        uint2 v1 = *(const uint2*)&tbuf[(long)s1 * 128 + q];
        uint2 v2 = *(const uint2*)&tbuf[(long)s2 * 128 + q];
        uint2 v3 = *(const uint2*)&tbuf[(long)s3 * 128 + q];
        a0 += (b2f((bfu)(v0.x & 0xffff)) + b2f((bfu)(v1.x & 0xffff))) +
              (b2f((bfu)(v2.x & 0xffff)) + b2f((bfu)(v3.x & 0xffff)));
        a1 += (b2f((bfu)(v0.x >> 16)) + b2f((bfu)(v1.x >> 16))) +
              (b2f((bfu)(v2.x >> 16)) + b2f((bfu)(v3.x >> 16)));
        a2 += (b2f((bfu)(v0.y & 0xffff)) + b2f((bfu)(v1.y & 0xffff))) +
              (b2f((bfu)(v2.y & 0xffff)) + b2f((bfu)(v3.y & 0xffff)));
        a3 += (b2f((bfu)(v0.y >> 16)) + b2f((bfu)(v1.y >> 16))) +
              (b2f((bfu)(v2.y >> 16)) + b2f((bfu)(v3.y >> 16)));
    }
    for (; e < end; ++e) {
        int s0 = col[e];
        uint2 v0 = *(const uint2*)&tbuf[(long)s0 * 128 + q];
        a0 += b2f((bfu)(v0.x & 0xffff));
        a1 += b2f((bfu)(v0.x >> 16));
        a2 += b2f((bfu)(v0.y & 0xffff));
        a3 += b2f((bfu)(v0.y >> 16));
    }
    const float dn = dis[node];
    float4 bb = *(const float4*)&b[q];
    float o0 = fmaxf(a0 * dn + bb.x, 0.0f);
    float o1 = fmaxf(a1 * dn + bb.y, 0.0f);
    float o2 = fmaxf(a2 * dn + bb.z, 0.0f);
    float o3 = fmaxf(a3 * dn + bb.w, 0.0f);
    uint2 pk;
    pk.x = (unsigned)f2b(o0) | ((unsigned)f2b(o1) << 16);
    pk.y = (unsigned)f2b(o2) | ((unsigned)f2b(o3) << 16);
    *(uint2*)&h[(long)node * 128 + q] = pk;
}

// ---------------- graph segment bounds (batch is sorted) ----------------
__global__ void k_bounds(const int* __restrict__ batch, int* __restrict__ bounds) {
    int g = blockIdx.x * blockDim.x + threadIdx.x;
    if (g > N_GRAPHS) return;
    int lo = 0, hi = N_NODES;
    while (lo < hi) {
        int mid = (lo + hi) >> 1;
        if (batch[mid] < g) lo = mid + 1; else hi = mid;
    }
    bounds[g] = lo;
}

// ---------------- fused pool (mean over segment; h already relu'd) + MLP head ----------------
__global__ __launch_bounds__(128) void k_pool_head(const int* __restrict__ bounds,
                                                   const bfu* __restrict__ h,
                                                   const float* __restrict__ fw1, const float* __restrict__ fb1,
                                                   const float* __restrict__ fw2, const float* __restrict__ fb2,
                                                   float* __restrict__ out) {
    const int g = blockIdx.x;
    const int t = threadIdx.x;
    const int s = bounds[g], e = bounds[g + 1];
    float sum = 0.0f;
    int n = s;
    for (; n + 1 < e; n += 2) {
        sum += b2f(h[(long)n * 128 + t]);
        sum += b2f(h[(long)(n + 1) * 128 + t]);
    }
    if (n < e) sum += b2f(h[(long)n * 128 + t]);

    __shared__ float sg[128];
    __shared__ float sh[32];
    float inv = 1.0f / fmaxf((float)(e - s), 1.0f);
    sg[t] = sum * inv;
    __syncthreads();
    if (t < 32) {
        float a = fb1[t];
#pragma unroll 8
        for (int k = 0; k < 128; ++k) a += sg[k] * fw1[k * 32 + t];
        sh[t] = fmaxf(a, 0.0f);
    }
    __syncthreads();
    if (t == 0) {
        float l0 = fb2[0], l1 = fb2[1];
        for (int k = 0; k < 32; ++k) {
            l0 += sh[k] * fw2[k * 2];
            l1 += sh[k] * fw2[k * 2 + 1];
        }
        float m = fmaxf(l0, l1);
        float lse = m + logf(expf(l0 - m) + expf(l1 - m));
        out[g * 2 + 0] = l0 - lse;
        out[g * 2 + 1] = l1 - lse;
    }
}

extern "C" void kernel_launch(void* const* d_in, const int* in_sizes, int n_in,
                              void* d_out, int out_size, void* d_ws, size_t ws_size,
                              hipStream_t stream) {
    const float* x  = (const float*)d_in[0];
    const int* ei   = (const int*)d_in[1];
    const int* batch = (const int*)d_in[2];
    const float* W1 = (const float*)d_in[3];
    const float* b1 = (const float*)d_in[4];
    const float* W2 = (const float*)d_in[5];
    const float* b2 = (const float*)d_in[6];
    const float* W3 = (const float*)d_in[7];
    const float* b3 = (const float*)d_in[8];
    const float* fw1 = (const float*)d_in[9];
    const float* fb1 = (const float*)d_in[10];
    const float* fw2 = (const float*)d_in[11];
    const float* fb2 = (const float*)d_in[12];
    float* out = (float*)d_out;

    const int* src = ei;
    const int* dst = ei + N_EDGES;

    // workspace layout (16B-aligned regions)
    char* ws = (char*)d_ws;
    int*   cnt     = (int*)ws;                                   // N ints (reused as cursor)
    float* dis     = (float*)(cnt + N_NODES);                    // N
    int*   row_ptr = (int*)(dis + N_NODES);                      // N+1 (+pad to 16B)
    int*   partial = row_ptr + N_NODES + 4;                      // 128 ints
    int*   bounds  = partial + 128;                              // G+1 (+pad)
    int*   col     = bounds + N_GRAPHS + 8;                      // E
    bfu*   wpack   = (bfu*)(col + N_EDGES);                      // up to 8*8*64*8 = 32768 bfu (64 KB)
    bfu*   buf0    = wpack + 32768;                              // N*128 bf16 (t')
    bfu*   buf1    = buf0 + (long)N_NODES * 128;                 // N*128 bf16 (h, post-relu)

    const int B = 256;
    // ---- CSR build + norms + segment bounds ----
    k_zero_cnt<<<(N_NODES + B - 1) / B, B, 0, stream>>>(cnt);
    k_cnt<<<(N_EDGES + B - 1) / B, B, 0, stream>>>(dst, cnt);
    k_dis<<<(N_NODES + B - 1) / B, B, 0, stream>>>(cnt, dis);
    k_scan1<<<SCAN_BLOCKS, 256, 0, stream>>>(cnt, row_ptr, partial);
    k_scan2<<<1, 128, 0, stream>>>(partial, row_ptr);
    k_scan3<<<SCAN_BLOCKS, 256, 0, stream>>>(row_ptr, cnt /*cursor*/, partial);
    k_fill<<<(N_EDGES + B - 1) / B, B, 0, stream>>>(src, dst, cnt /*cursor*/, col);
    k_bounds<<<(N_GRAPHS + 1 + 255) / 256, 256, 0, stream>>>(batch, bounds);

    const int mmGrid = (N_NODES + 127) / 128;   // 782
    const int aggGrid = (N_NODES + 7) / 8;

    // layer 1 (A = x fp32, K=256)
    k_wpack<<<16, 256, 0, stream>>>(W1, wpack, F_IN);
    k_mm_mfma<F_IN, float><<<mmGrid, 256, 0, stream>>>(x, wpack, dis, buf0, N_NODES);
    k_agg<<<aggGrid, 256, 0, stream>>>(row_ptr, col, dis, buf0, b1, buf1);
    // layer 2 (A = h bf16, K=128)
    k_wpack<<<8, 256, 0, stream>>>(W2, wpack, H_DIM);
    k_mm_mfma<H_DIM, bfu><<<mmGrid, 256, 0, stream>>>(buf1, wpack, dis, buf0, N_NODES);
    k_agg<<<aggGrid, 256, 0, stream>>>(row_ptr, col, dis, buf0, b2, buf1);
    // layer 3
    k_wpack<<<8, 256, 0, stream>>>(W3, wpack, H_DIM);
    k_mm_mfma<H_DIM, bfu><<<mmGrid, 256, 0, stream>>>(buf1, wpack, dis, buf0, N_NODES);
    k_agg<<<aggGrid, 256, 0, stream>>>(row_ptr, col, dis, buf0, b3, buf1);

    // fused pool + head
    k_pool_head<<<N_GRAPHS, 128, 0, stream>>>(bounds, buf1, fw1, fb1, fw2, fb2, out);
}

// Round 6
// 413.416 us; speedup vs baseline: 21.1615x; 1.4036x over previous
//
#include <hip/hip_runtime.h>
#include <hip/hip_bf16.h>
#include <math.h>

#define N_NODES 100000
#define N_EDGES 1600000
#define F_IN 256
#define H_DIM 128
#define N_GRAPHS 1000

#define NB_BUCKETS ((N_NODES + 255) >> 8)   // 391 buckets of 256 nodes
#define BSTRIDE 392
#define A_BLOCKS 256
#define EPB (N_EDGES / A_BLOCKS)            // 6250 edges per block (exact)

typedef unsigned short bfu;  // bf16 bit pattern
typedef short short8 __attribute__((ext_vector_type(8)));   // 8 bf16 = 4 VGPR
typedef float f32x4 __attribute__((ext_vector_type(4)));    // MFMA accum

__device__ __forceinline__ float b2f(bfu u) {
    union { unsigned int i; float f; } v;
    v.i = (unsigned int)u << 16;
    return v.f;
}
__device__ __forceinline__ bfu f2b(float f) {
    __hip_bfloat16 h = __float2bfloat16(f);  // RNE
    return *reinterpret_cast<bfu*>(&h);
}

// ---------------- CSR build: bucketed counting sort ----------------
// A1: per-block bucket histogram (bucket = dst >> 8)
__global__ __launch_bounds__(256) void k_hist(const int* __restrict__ dst,
                                              int* __restrict__ cnt_bb) {
    __shared__ int h[BSTRIDE];
    const int t = threadIdx.x;
    for (int i = t; i < BSTRIDE; i += 256) h[i] = 0;
    __syncthreads();
    const int base = blockIdx.x * EPB;
    for (int i = t; i < EPB; i += 256) atomicAdd(&h[dst[base + i] >> 8], 1);
    __syncthreads();
    for (int i = t; i < NB_BUCKETS; i += 256) cnt_bb[blockIdx.x * BSTRIDE + i] = h[i];
}

// s1: for each bucket, exclusive scan over blocks (in-place), bucket total out
__global__ __launch_bounds__(256) void k_scan_blocks(int* __restrict__ cnt_bb,
                                                     int* __restrict__ btot) {
    __shared__ int s[256];
    const int t = threadIdx.x;
    const int b = blockIdx.x;
    int v = cnt_bb[t * BSTRIDE + b];
    s[t] = v;
    __syncthreads();
    for (int off = 1; off < 256; off <<= 1) {
        int u = (t >= off) ? s[t - off] : 0;
        __syncthreads();
        s[t] += u;
        __syncthreads();
    }
    cnt_bb[t * BSTRIDE + b] = s[t] - v;  // exclusive over blocks
    if (t == 255) btot[b] = s[255];
}

// s2: exclusive scan of bucket totals -> bucket_base
__global__ __launch_bounds__(512) void k_scan_buckets(const int* __restrict__ btot,
                                                      int* __restrict__ bucket_base) {
    __shared__ int s[512];
    const int t = threadIdx.x;
    int v = (t < NB_BUCKETS) ? btot[t] : 0;
    s[t] = v;
    __syncthreads();
    for (int off = 1; off < 512; off <<= 1) {
        int u = (t >= off) ? s[t - off] : 0;
        __syncthreads();
        s[t] += u;
        __syncthreads();
    }
    if (t < NB_BUCKETS) bucket_base[t] = s[t] - v;
    if (t == 0) bucket_base[NB_BUCKETS] = N_EDGES;
}

// A3: scatter edges into bucket-major staging, packed (dstlow<<24 | src)
__global__ __launch_bounds__(256) void k_stage(const int* __restrict__ src,
                                               const int* __restrict__ dst,
                                               const int* __restrict__ cnt_bb,
                                               const int* __restrict__ bucket_base,
                                               unsigned* __restrict__ staging) {
    __shared__ int cur[BSTRIDE];
    const int t = threadIdx.x;
    const int blk = blockIdx.x;
    for (int i = t; i < NB_BUCKETS; i += 256)
        cur[i] = bucket_base[i] + cnt_bb[blk * BSTRIDE + i];
    __syncthreads();
    const int base = blk * EPB;
    for (int i = t; i < EPB; i += 256) {
        int d = dst[base + i];
        int s = src[base + i];
        int b = d >> 8;
        int pos = atomicAdd(&cur[b], 1);
        staging[pos] = (unsigned)s | ((unsigned)(d & 255) << 24);
    }
}

// B: per bucket -> row_ptr, dis, col (all writes L2-resident)
__global__ __launch_bounds__(256) void k_bucket(const unsigned* __restrict__ staging,
                                                const int* __restrict__ bucket_base,
                                                int* __restrict__ row_ptr,
                                                float* __restrict__ dis,
                                                int* __restrict__ col) {
    __shared__ int h[256];
    __shared__ int sc[256];
    __shared__ int cur[256];
    const int t = threadIdx.x;
    const int b = blockIdx.x;
    const int s0 = bucket_base[b];
    const int ne = bucket_base[b + 1] - s0;
    h[t] = 0;
    __syncthreads();
    for (int i = t; i < ne; i += 256) atomicAdd(&h[staging[s0 + i] >> 24], 1);
    __syncthreads();
    int myc = h[t];
    sc[t] = myc;
    __syncthreads();
    for (int off = 1; off < 256; off <<= 1) {
        int u = (t >= off) ? sc[t - off] : 0;
        __syncthreads();
        sc[t] += u;
        __syncthreads();
    }
    int excl = sc[t] - myc;
    int node = b * 256 + t;
    if (node <= N_NODES) row_ptr[node] = s0 + excl;   // node==N_NODES -> E
    if (node < N_NODES) dis[node] = rsqrtf((float)(myc + 1));  // +1 self-loop
    cur[t] = s0 + excl;
    __syncthreads();
    for (int i = t; i < ne; i += 256) {
        unsigned u = staging[s0 + i];
        int pos = atomicAdd(&cur[u >> 24], 1);
        col[pos] = (int)(u & 0xFFFFFFu);
    }
}

// ---------------- W pre-pack: fp32 W[K][128] -> bf16 B-fragments ----------------
__global__ void k_wpack(const float* __restrict__ W, bfu* __restrict__ Wp, int K) {
    int u = blockIdx.x * 256 + threadIdx.x;
    int total = (K / 32) * 8 * 64;
    if (u >= total) return;
    int lane = u & 63;
    int nf = (u >> 6) & 7;
    int ks = u >> 9;
    int k = ks * 32 + (lane >> 4) * 8;
    int n = nf * 16 + (lane & 15);
    bfu o[8];
#pragma unroll
    for (int j = 0; j < 8; ++j) o[j] = f2b(W[(k + j) * 128 + n]);
    uint4 pk;
    pk.x = (unsigned)o[0] | ((unsigned)o[1] << 16);
    pk.y = (unsigned)o[2] | ((unsigned)o[3] << 16);
    pk.z = (unsigned)o[4] | ((unsigned)o[5] << 16);
    pk.w = (unsigned)o[6] | ((unsigned)o[7] << 16);
    *(uint4*)&Wp[u * 8] = pk;
}

// ---------------- MFMA GEMM: C[M,128](bf16) = A[M,K] @ W, row r scaled by dis[r] ----------------
template <int K, typename AT>
__global__ __launch_bounds__(256) void k_mm_mfma(const AT* __restrict__ A,
                                                 const bfu* __restrict__ Wp,
                                                 const float* __restrict__ dis,
                                                 bfu* __restrict__ C, int M) {
    __shared__ bfu As[128 * 40];  // 128 rows x 32 bf16, pitch 80 B
    const int t = threadIdx.x;
    const int w = t >> 6;
    const int l = t & 63;
    const int row0 = blockIdx.x * 128;
    const int l15 = l & 15;
    const int lhi = l >> 4;

    f32x4 acc[8][2];
#pragma unroll
    for (int nf = 0; nf < 8; ++nf)
#pragma unroll
        for (int mf = 0; mf < 2; ++mf) acc[nf][mf] = (f32x4)0.0f;

    for (int ks = 0; ks < K / 32; ++ks) {
        const int k0 = ks * 32;
        if constexpr (sizeof(AT) == 4) {
#pragma unroll
            for (int i = 0; i < 4; ++i) {
                int idx = t + i * 256;
                int row = idx >> 3, slot = idx & 7;
                int gr = row0 + row;
                float4 v = make_float4(0.f, 0.f, 0.f, 0.f);
                if (gr < M) v = *(const float4*)&A[(long)gr * K + k0 + slot * 4];
                uint2 pk;
                pk.x = (unsigned)f2b(v.x) | ((unsigned)f2b(v.y) << 16);
                pk.y = (unsigned)f2b(v.z) | ((unsigned)f2b(v.w) << 16);
                *(uint2*)&As[row * 40 + slot * 4] = pk;
            }
        } else {
#pragma unroll
            for (int i = 0; i < 2; ++i) {
                int idx = t + i * 256;
                int row = idx >> 2, slot = idx & 3;
                int gr = row0 + row;
                uint4 v = make_uint4(0u, 0u, 0u, 0u);
                if (gr < M) v = *(const uint4*)&A[(long)gr * K + k0 + slot * 8];
                *(uint4*)&As[row * 40 + slot * 8] = v;
            }
        }
        __syncthreads();
        short8 a0 = *(const short8*)&As[(w * 32 + l15) * 40 + lhi * 8];
        short8 a1 = *(const short8*)&As[(w * 32 + 16 + l15) * 40 + lhi * 8];
        const bfu* wp = Wp + ((long)(ks * 8) * 64 + l) * 8;
#pragma unroll
        for (int nf = 0; nf < 8; ++nf) {
            short8 wf = *(const short8*)(wp + (long)nf * 64 * 8);
            acc[nf][0] = __builtin_amdgcn_mfma_f32_16x16x32_bf16(wf, a0, acc[nf][0], 0, 0, 0);
            acc[nf][1] = __builtin_amdgcn_mfma_f32_16x16x32_bf16(wf, a1, acc[nf][1], 0, 0, 0);
        }
        __syncthreads();
    }
#pragma unroll
    for (int mf = 0; mf < 2; ++mf) {
        int row = row0 + w * 32 + mf * 16 + l15;
        if (row < M) {
            float sc = dis[row];
            int nb0 = lhi * 4;
#pragma unroll
            for (int nf = 0; nf < 8; ++nf) {
                f32x4 ac = acc[nf][mf];
                uint2 pk;
                pk.x = (unsigned)f2b(ac[0] * sc) | ((unsigned)f2b(ac[1] * sc) << 16);
                pk.y = (unsigned)f2b(ac[2] * sc) | ((unsigned)f2b(ac[3] * sc) << 16);
                *(uint2*)&C[(long)row * 128 + nf * 16 + nb0] = pk;
            }
        }
    }
}

// ---------------- CSR gather aggregation (bf16 storage, fp32 accum) ----------------
__global__ __launch_bounds__(256) void k_agg(const int* __restrict__ row_ptr,
                                             const int* __restrict__ col,
                                             const float* __restrict__ dis,
                                             const bfu* __restrict__ tbuf,
                                             const float* __restrict__ b,
                                             bfu* __restrict__ h) {
    const int t = threadIdx.x;
    const int node = blockIdx.x * 8 + (t >> 5);
    const int lane = t & 31;
    if (node >= N_NODES) return;
    const int q = lane << 2;

    uint2 sv = *(const uint2*)&tbuf[(long)node * 128 + q];
    float a0 = b2f((bfu)(sv.x & 0xffff));
    float a1 = b2f((bfu)(sv.x >> 16));
    float a2 = b2f((bfu)(sv.y & 0xffff));
    float a3 = b2f((bfu)(sv.y >> 16));

    int e = row_ptr[node];
    const int end = row_ptr[node + 1];
    for (; e + 3 < end; e += 4) {
        int s0 = col[e], s1 = col[e + 1], s2 = col[e + 2], s3 = col[e + 3];
        uint2 v0 = *(const uint2*)&tbuf[(long)s0 * 128 + q];
        uint2 v1 = *(const uint2*)&tbuf[(long)s1 * 128 + q];
        uint2 v2 = *(const uint2*)&tbuf[(long)s2 * 128 + q];
        uint2 v3 = *(const uint2*)&tbuf[(long)s3 * 128 + q];
        a0 += (b2f((bfu)(v0.x & 0xffff)) + b2f((bfu)(v1.x & 0xffff))) +
              (b2f((bfu)(v2.x & 0xffff)) + b2f((bfu)(v3.x & 0xffff)));
        a1 += (b2f((bfu)(v0.x >> 16)) + b2f((bfu)(v1.x >> 16))) +
              (b2f((bfu)(v2.x >> 16)) + b2f((bfu)(v3.x >> 16)));
        a2 += (b2f((bfu)(v0.y & 0xffff)) + b2f((bfu)(v1.y & 0xffff))) +
              (b2f((bfu)(v2.y & 0xffff)) + b2f((bfu)(v3.y & 0xffff)));
        a3 += (b2f((bfu)(v0.y >> 16)) + b2f((bfu)(v1.y >> 16))) +
              (b2f((bfu)(v2.y >> 16)) + b2f((bfu)(v3.y >> 16)));
    }
    for (; e < end; ++e) {
        int s0 = col[e];
        uint2 v0 = *(const uint2*)&tbuf[(long)s0 * 128 + q];
        a0 += b2f((bfu)(v0.x & 0xffff));
        a1 += b2f((bfu)(v0.x >> 16));
        a2 += b2f((bfu)(v0.y & 0xffff));
        a3 += b2f((bfu)(v0.y >> 16));
    }
    const float dn = dis[node];
    float4 bb = *(const float4*)&b[q];
    float o0 = fmaxf(a0 * dn + bb.x, 0.0f);
    float o1 = fmaxf(a1 * dn + bb.y, 0.0f);
    float o2 = fmaxf(a2 * dn + bb.z, 0.0f);
    float o3 = fmaxf(a3 * dn + bb.w, 0.0f);
    uint2 pk;
    pk.x = (unsigned)f2b(o0) | ((unsigned)f2b(o1) << 16);
    pk.y = (unsigned)f2b(o2) | ((unsigned)f2b(o3) << 16);
    *(uint2*)&h[(long)node * 128 + q] = pk;
}

// ---------------- graph segment bounds (batch is sorted) ----------------
__global__ void k_bounds(const int* __restrict__ batch, int* __restrict__ bounds) {
    int g = blockIdx.x * blockDim.x + threadIdx.x;
    if (g > N_GRAPHS) return;
    int lo = 0, hi = N_NODES;
    while (lo < hi) {
        int mid = (lo + hi) >> 1;
        if (batch[mid] < g) lo = mid + 1; else hi = mid;
    }
    bounds[g] = lo;
}

// ---------------- fused pool (mean over segment; h already relu'd) + MLP head ----------------
__global__ __launch_bounds__(128) void k_pool_head(const int* __restrict__ bounds,
                                                   const bfu* __restrict__ h,
                                                   const float* __restrict__ fw1, const float* __restrict__ fb1,
                                                   const float* __restrict__ fw2, const float* __restrict__ fb2,
                                                   float* __restrict__ out) {
    const int g = blockIdx.x;
    const int t = threadIdx.x;
    const int s = bounds[g], e = bounds[g + 1];
    float sum = 0.0f;
    int n = s;
    for (; n + 1 < e; n += 2) {
        sum += b2f(h[(long)n * 128 + t]);
        sum += b2f(h[(long)(n + 1) * 128 + t]);
    }
    if (n < e) sum += b2f(h[(long)n * 128 + t]);

    __shared__ float sg[128];
    __shared__ float sh[32];
    float inv = 1.0f / fmaxf((float)(e - s), 1.0f);
    sg[t] = sum * inv;
    __syncthreads();
    if (t < 32) {
        float a = fb1[t];
#pragma unroll 8
        for (int k = 0; k < 128; ++k) a += sg[k] * fw1[k * 32 + t];
        sh[t] = fmaxf(a, 0.0f);
    }
    __syncthreads();
    if (t == 0) {
        float l0 = fb2[0], l1 = fb2[1];
        for (int k = 0; k < 32; ++k) {
            l0 += sh[k] * fw2[k * 2];
            l1 += sh[k] * fw2[k * 2 + 1];
        }
        float m = fmaxf(l0, l1);
        float lse = m + logf(expf(l0 - m) + expf(l1 - m));
        out[g * 2 + 0] = l0 - lse;
        out[g * 2 + 1] = l1 - lse;
    }
}

extern "C" void kernel_launch(void* const* d_in, const int* in_sizes, int n_in,
                              void* d_out, int out_size, void* d_ws, size_t ws_size,
                              hipStream_t stream) {
    const float* x  = (const float*)d_in[0];
    const int* ei   = (const int*)d_in[1];
    const int* batch = (const int*)d_in[2];
    const float* W1 = (const float*)d_in[3];
    const float* b1 = (const float*)d_in[4];
    const float* W2 = (const float*)d_in[5];
    const float* b2 = (const float*)d_in[6];
    const float* W3 = (const float*)d_in[7];
    const float* b3 = (const float*)d_in[8];
    const float* fw1 = (const float*)d_in[9];
    const float* fb1 = (const float*)d_in[10];
    const float* fw2 = (const float*)d_in[11];
    const float* fb2 = (const float*)d_in[12];
    float* out = (float*)d_out;

    const int* src = ei;
    const int* dst = ei + N_EDGES;

    // workspace layout (all chunks multiple of 16 B)
    char* ws = (char*)d_ws;
    int*      cnt_bb      = (int*)ws;                            // 256*392
    int*      btot        = cnt_bb + A_BLOCKS * BSTRIDE;         // 392
    int*      bucket_base = btot + BSTRIDE;                      // 392+8
    unsigned* staging     = (unsigned*)(bucket_base + BSTRIDE + 8);  // E
    int*      row_ptr     = (int*)(staging + N_EDGES);           // N+4
    float*    dis         = (float*)(row_ptr + N_NODES + 4);     // N
    int*      col         = (int*)(dis + N_NODES);               // E
    int*      bounds      = col + N_EDGES;                       // G+1 (+pad)
    bfu*      wpack       = (bfu*)(bounds + N_GRAPHS + 8);       // 32768 bfu
    bfu*      buf0        = wpack + 32768;                       // N*128 bf16 (t')
    bfu*      buf1        = buf0 + (long)N_NODES * 128;          // N*128 bf16 (h)

    // ---- CSR build (counting sort) + norms + segment bounds ----
    k_hist<<<A_BLOCKS, 256, 0, stream>>>(dst, cnt_bb);
    k_scan_blocks<<<NB_BUCKETS, 256, 0, stream>>>(cnt_bb, btot);
    k_scan_buckets<<<1, 512, 0, stream>>>(btot, bucket_base);
    k_stage<<<A_BLOCKS, 256, 0, stream>>>(src, dst, cnt_bb, bucket_base, staging);
    k_bucket<<<NB_BUCKETS, 256, 0, stream>>>(staging, bucket_base, row_ptr, dis, col);
    k_bounds<<<(N_GRAPHS + 1 + 255) / 256, 256, 0, stream>>>(batch, bounds);

    const int mmGrid = (N_NODES + 127) / 128;
    const int aggGrid = (N_NODES + 7) / 8;

    // layer 1 (A = x fp32, K=256)
    k_wpack<<<16, 256, 0, stream>>>(W1, wpack, F_IN);
    k_mm_mfma<F_IN, float><<<mmGrid, 256, 0, stream>>>(x, wpack, dis, buf0, N_NODES);
    k_agg<<<aggGrid, 256, 0, stream>>>(row_ptr, col, dis, buf0, b1, buf1);
    // layer 2 (A = h bf16, K=128)
    k_wpack<<<8, 256, 0, stream>>>(W2, wpack, H_DIM);
    k_mm_mfma<H_DIM, bfu><<<mmGrid, 256, 0, stream>>>(buf1, wpack, dis, buf0, N_NODES);
    k_agg<<<aggGrid, 256, 0, stream>>>(row_ptr, col, dis, buf0, b2, buf1);
    // layer 3
    k_wpack<<<8, 256, 0, stream>>>(W3, wpack, H_DIM);
    k_mm_mfma<H_DIM, bfu><<<mmGrid, 256, 0, stream>>>(buf1, wpack, dis, buf0, N_NODES);
    k_agg<<<aggGrid, 256, 0, stream>>>(row_ptr, col, dis, buf0, b3, buf1);

    // fused pool + head
    k_pool_head<<<N_GRAPHS, 128, 0, stream>>>(bounds, buf1, fw1, fb1, fw2, fb2, out);
}

// Round 7
// 410.030 us; speedup vs baseline: 21.3362x; 1.0083x over previous
//
#include <hip/hip_runtime.h>
#include <hip/hip_bf16.h>
#include <math.h>

#define N_NODES 100000
#define N_EDGES 1600000
#define F_IN 256
#define H_DIM 128
#define N_GRAPHS 1000

#define NB_BUCKETS ((N_NODES + 255) >> 8)   // 391 buckets of 256 nodes
#define BSTRIDE 392
#define A_BLOCKS 256
#define EPB (N_EDGES / A_BLOCKS)            // 6250 edges per block (exact)

typedef unsigned short bfu;  // bf16 bit pattern
typedef short short8 __attribute__((ext_vector_type(8)));   // 8 bf16 = 4 VGPR
typedef float f32x4 __attribute__((ext_vector_type(4)));    // MFMA accum

__device__ __forceinline__ float b2f(unsigned u) {
    union { unsigned int i; float f; } v;
    v.i = u << 16;
    return v.f;
}
__device__ __forceinline__ bfu f2b(float f) {
    __hip_bfloat16 h = __float2bfloat16(f);  // RNE
    return *reinterpret_cast<bfu*>(&h);
}

// ---------------- CSR build: bucketed counting sort ----------------
__global__ __launch_bounds__(256) void k_hist(const int* __restrict__ dst,
                                              int* __restrict__ cnt_bb) {
    __shared__ int h[BSTRIDE];
    const int t = threadIdx.x;
    for (int i = t; i < BSTRIDE; i += 256) h[i] = 0;
    __syncthreads();
    const int base = blockIdx.x * EPB;
    for (int i = t; i < EPB; i += 256) atomicAdd(&h[dst[base + i] >> 8], 1);
    __syncthreads();
    for (int i = t; i < NB_BUCKETS; i += 256) cnt_bb[blockIdx.x * BSTRIDE + i] = h[i];
}

__global__ __launch_bounds__(256) void k_scan_blocks(int* __restrict__ cnt_bb,
                                                     int* __restrict__ btot) {
    __shared__ int s[256];
    const int t = threadIdx.x;
    const int b = blockIdx.x;
    int v = cnt_bb[t * BSTRIDE + b];
    s[t] = v;
    __syncthreads();
    for (int off = 1; off < 256; off <<= 1) {
        int u = (t >= off) ? s[t - off] : 0;
        __syncthreads();
        s[t] += u;
        __syncthreads();
    }
    cnt_bb[t * BSTRIDE + b] = s[t] - v;
    if (t == 255) btot[b] = s[255];
}

__global__ __launch_bounds__(512) void k_scan_buckets(const int* __restrict__ btot,
                                                      int* __restrict__ bucket_base) {
    __shared__ int s[512];
    const int t = threadIdx.x;
    int v = (t < NB_BUCKETS) ? btot[t] : 0;
    s[t] = v;
    __syncthreads();
    for (int off = 1; off < 512; off <<= 1) {
        int u = (t >= off) ? s[t - off] : 0;
        __syncthreads();
        s[t] += u;
        __syncthreads();
    }
    if (t < NB_BUCKETS) bucket_base[t] = s[t] - v;
    if (t == 0) bucket_base[NB_BUCKETS] = N_EDGES;
}

__global__ __launch_bounds__(256) void k_stage(const int* __restrict__ src,
                                               const int* __restrict__ dst,
                                               const int* __restrict__ cnt_bb,
                                               const int* __restrict__ bucket_base,
                                               unsigned* __restrict__ staging) {
    __shared__ int cur[BSTRIDE];
    const int t = threadIdx.x;
    const int blk = blockIdx.x;
    for (int i = t; i < NB_BUCKETS; i += 256)
        cur[i] = bucket_base[i] + cnt_bb[blk * BSTRIDE + i];
    __syncthreads();
    const int base = blk * EPB;
    for (int i = t; i < EPB; i += 256) {
        int d = dst[base + i];
        int s = src[base + i];
        int b = d >> 8;
        int pos = atomicAdd(&cur[b], 1);
        staging[pos] = (unsigned)s | ((unsigned)(d & 255) << 24);
    }
}

__global__ __launch_bounds__(256) void k_bucket(const unsigned* __restrict__ staging,
                                                const int* __restrict__ bucket_base,
                                                int* __restrict__ row_ptr,
                                                float* __restrict__ dis,
                                                int* __restrict__ col) {
    __shared__ int h[256];
    __shared__ int sc[256];
    __shared__ int cur[256];
    const int t = threadIdx.x;
    const int b = blockIdx.x;
    const int s0 = bucket_base[b];
    const int ne = bucket_base[b + 1] - s0;
    h[t] = 0;
    __syncthreads();
    for (int i = t; i < ne; i += 256) atomicAdd(&h[staging[s0 + i] >> 24], 1);
    __syncthreads();
    int myc = h[t];
    sc[t] = myc;
    __syncthreads();
    for (int off = 1; off < 256; off <<= 1) {
        int u = (t >= off) ? sc[t - off] : 0;
        __syncthreads();
        sc[t] += u;
        __syncthreads();
    }
    int excl = sc[t] - myc;
    int node = b * 256 + t;
    if (node <= N_NODES) row_ptr[node] = s0 + excl;
    if (node < N_NODES) dis[node] = rsqrtf((float)(myc + 1));
    cur[t] = s0 + excl;
    __syncthreads();
    for (int i = t; i < ne; i += 256) {
        unsigned u = staging[s0 + i];
        int pos = atomicAdd(&cur[u >> 24], 1);
        col[pos] = (int)(u & 0xFFFFFFu);
    }
}

// ---------------- W pre-pack: fp32 W[K][128] -> bf16 B-fragments ----------------
__global__ void k_wpack(const float* __restrict__ W, bfu* __restrict__ Wp, int K) {
    int u = blockIdx.x * 256 + threadIdx.x;
    int total = (K / 32) * 8 * 64;
    if (u >= total) return;
    int lane = u & 63;
    int nf = (u >> 6) & 7;
    int ks = u >> 9;
    int k = ks * 32 + (lane >> 4) * 8;
    int n = nf * 16 + (lane & 15);
    bfu o[8];
#pragma unroll
    for (int j = 0; j < 8; ++j) o[j] = f2b(W[(k + j) * 128 + n]);
    uint4 pk;
    pk.x = (unsigned)o[0] | ((unsigned)o[1] << 16);
    pk.y = (unsigned)o[2] | ((unsigned)o[3] << 16);
    pk.z = (unsigned)o[4] | ((unsigned)o[5] << 16);
    pk.w = (unsigned)o[6] | ((unsigned)o[7] << 16);
    *(uint4*)&Wp[u * 8] = pk;
}

// ---------------- MFMA GEMM v2: 64-row tile, dbuf LDS + register prefetch ----------------
// 256 threads = 4 waves; wave w owns rows w*16..w*16+15, all 128 cols.
// acc[nf] = mfma(Wfrag[nf], Afrag) -> lane holds C[row = w*16 + (l&15)][n = nf*16 + (l>>4)*4 + reg].
template <int K, typename AT>
__global__ __launch_bounds__(256) void k_mm_mfma(const AT* __restrict__ A,
                                                 const bfu* __restrict__ Wp,
                                                 const float* __restrict__ dis,
                                                 bfu* __restrict__ C, int M) {
    __shared__ bfu As[2][64 * 40];   // 64 rows x 32 bf16, pitch 80 B, double-buffered
    const int t = threadIdx.x;
    const int w = t >> 6;
    const int l = t & 63;
    const int l15 = l & 15;
    const int lhi = l >> 4;
    const int row0 = blockIdx.x * 64;
    constexpr int KS = K / 32;

    f32x4 acc[8];
#pragma unroll
    for (int nf = 0; nf < 8; ++nf) acc[nf] = (f32x4)0.0f;

    // prefetch registers
    float4 pf0 = make_float4(0.f, 0.f, 0.f, 0.f), pf1 = pf0;  // fp32 path
    uint4 pb = make_uint4(0u, 0u, 0u, 0u);                    // bf16 path

    // ---- load ks=0 ----
    if constexpr (sizeof(AT) == 4) {
        int r0 = t >> 3, s0 = t & 7;
        int r1 = (t + 256) >> 3, s1 = t & 7;
        if (row0 + r0 < M) pf0 = *(const float4*)&A[(long)(row0 + r0) * K + s0 * 4];
        if (row0 + r1 < M) pf1 = *(const float4*)&A[(long)(row0 + r1) * K + s1 * 4];
    } else {
        int r = t >> 2, s = t & 3;
        if (row0 + r < M) pb = *(const uint4*)&A[(long)(row0 + r) * K + s * 8];
    }

    int buf = 0;
    for (int ks = 0; ks < KS; ++ks) {
        // ---- store prefetched slab into As[buf] ----
        if constexpr (sizeof(AT) == 4) {
            int r0 = t >> 3, s0 = t & 7;
            int r1 = (t + 256) >> 3;
            uint2 pk0, pk1;
            pk0.x = (unsigned)f2b(pf0.x) | ((unsigned)f2b(pf0.y) << 16);
            pk0.y = (unsigned)f2b(pf0.z) | ((unsigned)f2b(pf0.w) << 16);
            pk1.x = (unsigned)f2b(pf1.x) | ((unsigned)f2b(pf1.y) << 16);
            pk1.y = (unsigned)f2b(pf1.z) | ((unsigned)f2b(pf1.w) << 16);
            *(uint2*)&As[buf][r0 * 40 + s0 * 4] = pk0;
            *(uint2*)&As[buf][r1 * 40 + s0 * 4] = pk1;
        } else {
            *(uint4*)&As[buf][(t >> 2) * 40 + (t & 3) * 8] = pb;
        }
        // ---- issue loads for ks+1 (overlap with barrier+MFMA) ----
        if (ks + 1 < KS) {
            const int k0n = (ks + 1) * 32;
            if constexpr (sizeof(AT) == 4) {
                int r0 = t >> 3, s0 = t & 7;
                int r1 = (t + 256) >> 3;
                pf0 = make_float4(0.f, 0.f, 0.f, 0.f);
                pf1 = pf0;
                if (row0 + r0 < M) pf0 = *(const float4*)&A[(long)(row0 + r0) * K + k0n + s0 * 4];
                if (row0 + r1 < M) pf1 = *(const float4*)&A[(long)(row0 + r1) * K + k0n + s0 * 4];
            } else {
                int r = t >> 2, s = t & 3;
                pb = make_uint4(0u, 0u, 0u, 0u);
                if (row0 + r < M) pb = *(const uint4*)&A[(long)(row0 + r) * K + k0n + s * 8];
            }
        }
        __syncthreads();
        // ---- fragments + MFMA ----
        short8 af = *(const short8*)&As[buf][(w * 16 + l15) * 40 + lhi * 8];
        const bfu* wp = Wp + ((long)(ks * 8) * 64 + l) * 8;
#pragma unroll
        for (int nf = 0; nf < 8; ++nf) {
            short8 wf = *(const short8*)(wp + (long)nf * 64 * 8);
            acc[nf] = __builtin_amdgcn_mfma_f32_16x16x32_bf16(wf, af, acc[nf], 0, 0, 0);
        }
        buf ^= 1;
    }
    // ---- epilogue ----
    int row = row0 + w * 16 + l15;
    if (row < M) {
        float sc = dis[row];
        int nb0 = lhi * 4;
#pragma unroll
        for (int nf = 0; nf < 8; ++nf) {
            uint2 pk;
            pk.x = (unsigned)f2b(acc[nf][0] * sc) | ((unsigned)f2b(acc[nf][1] * sc) << 16);
            pk.y = (unsigned)f2b(acc[nf][2] * sc) | ((unsigned)f2b(acc[nf][3] * sc) << 16);
            *(uint2*)&C[(long)row * 128 + nf * 16 + nb0] = pk;
        }
    }
}

// ---------------- CSR gather aggregation v2: 16 lanes/node, uint4 gathers, 8-edge unroll ----------------
__global__ __launch_bounds__(256) void k_agg(const int* __restrict__ row_ptr,
                                             const int* __restrict__ col,
                                             const float* __restrict__ dis,
                                             const bfu* __restrict__ tbuf,
                                             const float* __restrict__ b,
                                             bfu* __restrict__ h) {
    const int t = threadIdx.x;
    const int node = blockIdx.x * 16 + (t >> 4);  // 16 nodes/block, 16-lane group each
    const int lane = t & 15;
    if (node >= N_NODES) return;
    const int ch = lane << 3;  // 8 channels per lane (16 B)

    uint4 sv = *(const uint4*)&tbuf[(long)node * 128 + ch];
    float a0 = b2f(sv.x & 0xffff), a1 = b2f(sv.x >> 16);
    float a2 = b2f(sv.y & 0xffff), a3 = b2f(sv.y >> 16);
    float a4 = b2f(sv.z & 0xffff), a5 = b2f(sv.z >> 16);
    float a6 = b2f(sv.w & 0xffff), a7 = b2f(sv.w >> 16);

    int e = row_ptr[node];
    const int end = row_ptr[node + 1];
    for (; e + 7 < end; e += 8) {
        int s[8];
#pragma unroll
        for (int j = 0; j < 8; ++j) s[j] = col[e + j];
        uint4 v[8];
#pragma unroll
        for (int j = 0; j < 8; ++j) v[j] = *(const uint4*)&tbuf[(long)s[j] * 128 + ch];
#pragma unroll
        for (int j = 0; j < 8; ++j) {
            a0 += b2f(v[j].x & 0xffff); a1 += b2f(v[j].x >> 16);
            a2 += b2f(v[j].y & 0xffff); a3 += b2f(v[j].y >> 16);
            a4 += b2f(v[j].z & 0xffff); a5 += b2f(v[j].z >> 16);
            a6 += b2f(v[j].w & 0xffff); a7 += b2f(v[j].w >> 16);
        }
    }
    for (; e < end; ++e) {
        uint4 v = *(const uint4*)&tbuf[(long)col[e] * 128 + ch];
        a0 += b2f(v.x & 0xffff); a1 += b2f(v.x >> 16);
        a2 += b2f(v.y & 0xffff); a3 += b2f(v.y >> 16);
        a4 += b2f(v.z & 0xffff); a5 += b2f(v.z >> 16);
        a6 += b2f(v.w & 0xffff); a7 += b2f(v.w >> 16);
    }
    const float dn = dis[node];
    float4 bb0 = *(const float4*)&b[ch];
    float4 bb1 = *(const float4*)&b[ch + 4];
    float o0 = fmaxf(a0 * dn + bb0.x, 0.0f);
    float o1 = fmaxf(a1 * dn + bb0.y, 0.0f);
    float o2 = fmaxf(a2 * dn + bb0.z, 0.0f);
    float o3 = fmaxf(a3 * dn + bb0.w, 0.0f);
    float o4 = fmaxf(a4 * dn + bb1.x, 0.0f);
    float o5 = fmaxf(a5 * dn + bb1.y, 0.0f);
    float o6 = fmaxf(a6 * dn + bb1.z, 0.0f);
    float o7 = fmaxf(a7 * dn + bb1.w, 0.0f);
    uint4 pk;
    pk.x = (unsigned)f2b(o0) | ((unsigned)f2b(o1) << 16);
    pk.y = (unsigned)f2b(o2) | ((unsigned)f2b(o3) << 16);
    pk.z = (unsigned)f2b(o4) | ((unsigned)f2b(o5) << 16);
    pk.w = (unsigned)f2b(o6) | ((unsigned)f2b(o7) << 16);
    *(uint4*)&h[(long)node * 128 + ch] = pk;
}

// ---------------- graph segment bounds (batch is sorted) ----------------
__global__ void k_bounds(const int* __restrict__ batch, int* __restrict__ bounds) {
    int g = blockIdx.x * blockDim.x + threadIdx.x;
    if (g > N_GRAPHS) return;
    int lo = 0, hi = N_NODES;
    while (lo < hi) {
        int mid = (lo + hi) >> 1;
        if (batch[mid] < g) lo = mid + 1; else hi = mid;
    }
    bounds[g] = lo;
}

// ---------------- fused pool (mean over segment; h already relu'd) + MLP head ----------------
__global__ __launch_bounds__(128) void k_pool_head(const int* __restrict__ bounds,
                                                   const bfu* __restrict__ h,
                                                   const float* __restrict__ fw1, const float* __restrict__ fb1,
                                                   const float* __restrict__ fw2, const float* __restrict__ fb2,
                                                   float* __restrict__ out) {
    const int g = blockIdx.x;
    const int t = threadIdx.x;
    const int s = bounds[g], e = bounds[g + 1];
    float sum = 0.0f;
    int n = s;
    for (; n + 1 < e; n += 2) {
        sum += b2f(h[(long)n * 128 + t]);
        sum += b2f(h[(long)(n + 1) * 128 + t]);
    }
    if (n < e) sum += b2f(h[(long)n * 128 + t]);

    __shared__ float sg[128];
    __shared__ float sh[32];
    float inv = 1.0f / fmaxf((float)(e - s), 1.0f);
    sg[t] = sum * inv;
    __syncthreads();
    if (t < 32) {
        float a = fb1[t];
#pragma unroll 8
        for (int k = 0; k < 128; ++k) a += sg[k] * fw1[k * 32 + t];
        sh[t] = fmaxf(a, 0.0f);
    }
    __syncthreads();
    if (t == 0) {
        float l0 = fb2[0], l1 = fb2[1];
        for (int k = 0; k < 32; ++k) {
            l0 += sh[k] * fw2[k * 2];
            l1 += sh[k] * fw2[k * 2 + 1];
        }
        float m = fmaxf(l0, l1);
        float lse = m + logf(expf(l0 - m) + expf(l1 - m));
        out[g * 2 + 0] = l0 - lse;
        out[g * 2 + 1] = l1 - lse;
    }
}

extern "C" void kernel_launch(void* const* d_in, const int* in_sizes, int n_in,
                              void* d_out, int out_size, void* d_ws, size_t ws_size,
                              hipStream_t stream) {
    const float* x  = (const float*)d_in[0];
    const int* ei   = (const int*)d_in[1];
    const int* batch = (const int*)d_in[2];
    const float* W1 = (const float*)d_in[3];
    const float* b1 = (const float*)d_in[4];
    const float* W2 = (const float*)d_in[5];
    const float* b2 = (const float*)d_in[6];
    const float* W3 = (const float*)d_in[7];
    const float* b3 = (const float*)d_in[8];
    const float* fw1 = (const float*)d_in[9];
    const float* fb1 = (const float*)d_in[10];
    const float* fw2 = (const float*)d_in[11];
    const float* fb2 = (const float*)d_in[12];
    float* out = (float*)d_out;

    const int* src = ei;
    const int* dst = ei + N_EDGES;

    // workspace layout (all chunks multiple of 16 B)
    char* ws = (char*)d_ws;
    int*      cnt_bb      = (int*)ws;                            // 256*392
    int*      btot        = cnt_bb + A_BLOCKS * BSTRIDE;         // 392
    int*      bucket_base = btot + BSTRIDE;                      // 392+8
    unsigned* staging     = (unsigned*)(bucket_base + BSTRIDE + 8);  // E
    int*      row_ptr     = (int*)(staging + N_EDGES);           // N+4
    float*    dis         = (float*)(row_ptr + N_NODES + 4);     // N
    int*      col         = (int*)(dis + N_NODES);               // E
    int*      bounds      = col + N_EDGES;                       // G+1 (+pad)
    bfu*      wpack       = (bfu*)(bounds + N_GRAPHS + 8);       // 32768 bfu
    bfu*      buf0        = wpack + 32768;                       // N*128 bf16 (t')
    bfu*      buf1        = buf0 + (long)N_NODES * 128;          // N*128 bf16 (h)

    // ---- CSR build (counting sort) + norms + segment bounds ----
    k_hist<<<A_BLOCKS, 256, 0, stream>>>(dst, cnt_bb);
    k_scan_blocks<<<NB_BUCKETS, 256, 0, stream>>>(cnt_bb, btot);
    k_scan_buckets<<<1, 512, 0, stream>>>(btot, bucket_base);
    k_stage<<<A_BLOCKS, 256, 0, stream>>>(src, dst, cnt_bb, bucket_base, staging);
    k_bucket<<<NB_BUCKETS, 256, 0, stream>>>(staging, bucket_base, row_ptr, dis, col);
    k_bounds<<<(N_GRAPHS + 1 + 255) / 256, 256, 0, stream>>>(batch, bounds);

    const int mmGrid = (N_NODES + 63) / 64;    // 1563
    const int aggGrid = (N_NODES + 15) / 16;   // 6250

    // layer 1 (A = x fp32, K=256)
    k_wpack<<<16, 256, 0, stream>>>(W1, wpack, F_IN);
    k_mm_mfma<F_IN, float><<<mmGrid, 256, 0, stream>>>(x, wpack, dis, buf0, N_NODES);
    k_agg<<<aggGrid, 256, 0, stream>>>(row_ptr, col, dis, buf0, b1, buf1);
    // layer 2 (A = h bf16, K=128)
    k_wpack<<<8, 256, 0, stream>>>(W2, wpack, H_DIM);
    k_mm_mfma<H_DIM, bfu><<<mmGrid, 256, 0, stream>>>(buf1, wpack, dis, buf0, N_NODES);
    k_agg<<<aggGrid, 256, 0, stream>>>(row_ptr, col, dis, buf0, b2, buf1);
    // layer 3
    k_wpack<<<8, 256, 0, stream>>>(W3, wpack, H_DIM);
    k_mm_mfma<H_DIM, bfu><<<mmGrid, 256, 0, stream>>>(buf1, wpack, dis, buf0, N_NODES);
    k_agg<<<aggGrid, 256, 0, stream>>>(row_ptr, col, dis, buf0, b3, buf1);

    // fused pool + head
    k_pool_head<<<N_GRAPHS, 128, 0, stream>>>(bounds, buf1, fw1, fb1, fw2, fb2, out);
}